// Round 5
// baseline (1349.248 us; speedup 1.0000x reference)
//
#include <hip/hip_runtime.h>

#define S_ 1024
#define D_ 512
#define DCH 16      // denom chunk length
#define NDCH 64     // chunks per batch

// ---------------------------------------------------------------------------
// GEMM + bias + activation.  C[m,n] = act(sum_k A[m,k]*B[k,n] + bias[n])
// MODE 0: proj   A=x   (lda 512),  B=W_in (ldb 2048), N=1536, tanh for n<1024
// MODE 1: gates  A=v   (lda 1536), B=W_ig/W_fg/W_og (ldb 512), sigmoid;
//                g==0 (i-gate) fused to i*k (k read from qkv).
// MODE 2: out    A=hs  (lda 512),  B=W_out (ldb 512), N=512, no act
// ---------------------------------------------------------------------------
template<int MODE>
__global__ __launch_bounds__(256)
void gemm_act(const float* __restrict__ A, int lda,
              const float* __restrict__ W0, const float* __restrict__ W1,
              const float* __restrict__ W2,
              const float* __restrict__ bb0, const float* __restrict__ bb1,
              const float* __restrict__ bb2,
              float* __restrict__ Co, int ldc)
{
    const int tid = threadIdx.x;
    const int n0  = blockIdx.x * 128;
    const int m0  = blockIdx.y * 128;

    const float* Bp; const float* bias; int ldb;
    if (MODE == 1) {
        const int g  = n0 >> 9;
        const int nn = n0 & 511;
        Bp   = (g == 0 ? W0 : g == 1 ? W1 : W2) + nn;
        bias = (g == 0 ? bb0 : g == 1 ? bb1 : bb2) + nn;
        ldb  = 512;
    } else {
        Bp   = W0 + n0;
        bias = bb0 + n0;
        ldb  = (MODE == 0 ? 2048 : 512);
    }

    __shared__ float As[16][128];   // K-major
    __shared__ float Bs[16][128];

    float acc[8][8];
#pragma unroll
    for (int i = 0; i < 8; ++i)
#pragma unroll
        for (int j = 0; j < 8; ++j) acc[i][j] = 0.f;

    const int ar = tid >> 2;
    const int ac = (tid & 3) * 4;
    const int br = tid >> 5;
    const int bc = (tid & 31) * 4;
    const int ty = tid >> 4;
    const int tx = tid & 15;

    const float* Ap = A + (size_t)(m0 + ar) * lda + ac;
    const float* Bq = Bp + (size_t)br * ldb + bc;

    for (int k0 = 0; k0 < 512; k0 += 16) {
        float4 a0 = *(const float4*)(Ap);
        float4 a1 = *(const float4*)(Ap + (size_t)64 * lda);
        float4 b0 = *(const float4*)(Bq);
        float4 b1 = *(const float4*)(Bq + (size_t)8 * ldb);
        Ap += 16; Bq += (size_t)16 * ldb;

        __syncthreads();
        As[ac + 0][ar]      = a0.x; As[ac + 1][ar]      = a0.y;
        As[ac + 2][ar]      = a0.z; As[ac + 3][ar]      = a0.w;
        As[ac + 0][ar + 64] = a1.x; As[ac + 1][ar + 64] = a1.y;
        As[ac + 2][ar + 64] = a1.z; As[ac + 3][ar + 64] = a1.w;
        *(float4*)&Bs[br][bc]     = b0;
        *(float4*)&Bs[br + 8][bc] = b1;
        __syncthreads();

#pragma unroll
        for (int kk = 0; kk < 16; ++kk) {
            float4 aL = *(const float4*)&As[kk][ty * 4];
            float4 aH = *(const float4*)&As[kk][64 + ty * 4];
            float4 bL = *(const float4*)&Bs[kk][tx * 4];
            float4 bH = *(const float4*)&Bs[kk][64 + tx * 4];
            float av[8] = {aL.x, aL.y, aL.z, aL.w, aH.x, aH.y, aH.z, aH.w};
            float bv[8] = {bL.x, bL.y, bL.z, bL.w, bH.x, bH.y, bH.z, bH.w};
#pragma unroll
            for (int i = 0; i < 8; ++i)
#pragma unroll
                for (int j = 0; j < 8; ++j)
                    acc[i][j] = fmaf(av[i], bv[j], acc[i][j]);
        }
    }

    float bv[8];
#pragma unroll
    for (int j = 0; j < 8; ++j) {
        const int c = (j < 4) ? (tx * 4 + j) : (64 + tx * 4 + j - 4);
        bv[j] = bias[c];
    }
#pragma unroll
    for (int i = 0; i < 8; ++i) {
        const int m = m0 + ((i < 4) ? (ty * 4 + i) : (64 + ty * 4 + i - 4));
        float vals[8];
#pragma unroll
        for (int j = 0; j < 8; ++j) {
            float v = acc[i][j] + bv[j];
            if (MODE == 0) {
                const int cg = n0 + ((j < 4) ? (tx * 4 + j) : (64 + tx * 4 + j - 4));
                if (cg < 1024) v = tanhf(v);
            } else if (MODE == 1) {
                v = 1.0f / (1.0f + expf(-v));
            }
            vals[j] = v;
        }
        if (MODE == 1 && n0 < 512) {
            const float* krow = A + (size_t)m * lda - 512;
            float4 kl = *(const float4*)(krow + n0 + tx * 4);
            float4 kh = *(const float4*)(krow + n0 + 64 + tx * 4);
            vals[0] *= kl.x; vals[1] *= kl.y; vals[2] *= kl.z; vals[3] *= kl.w;
            vals[4] *= kh.x; vals[5] *= kh.y; vals[6] *= kh.z; vals[7] *= kh.w;
        }
        float* row = Co + (size_t)m * ldc + n0;
        *(float4*)&row[tx * 4]      = make_float4(vals[0], vals[1], vals[2], vals[3]);
        *(float4*)&row[64 + tx * 4] = make_float4(vals[4], vals[5], vals[6], vals[7]);
    }
}

// ---------------------------------------------------------------------------
// n-scan pipeline (f64):  local chunk-16 scans -> stitch -> per-chunk denom
// replay with one WAVE per chunk (no barriers) and T=4 batched fold-reduce.
// ---------------------------------------------------------------------------
__global__ __launch_bounds__(512)
void nscan_local(const float* __restrict__ GG,
                 double* __restrict__ nend, double* __restrict__ Dend)
{
    const int b = blockIdx.x >> 6;
    const int c = blockIdx.x & 63;
    const int d = threadIdx.x;
    const float* gb = GG + (size_t)b * S_ * 1536 + (size_t)c * DCH * 1536;
    double n = 0.0, P = 1.0;
    for (int u = 0; u < DCH; ++u) {
        const float* row = gb + (size_t)u * 1536;
        const double ik = (double)row[d];
        const double f  = (double)row[512 + d];
        n = fma(f, n, ik);
        P *= f;
    }
    nend[(size_t)blockIdx.x * 512 + d] = n;
    Dend[(size_t)blockIdx.x * 512 + d] = P;
}

__global__ __launch_bounds__(512)
void nscan_stitch(const double* __restrict__ nend, const double* __restrict__ Dend,
                  double* __restrict__ n0a, float* __restrict__ nfO)
{
    const int b = blockIdx.x;
    const int d = threadIdx.x;
    double n0 = 0.0;
    for (int c = 0; c < NDCH; ++c) {
        const size_t idx = ((size_t)(b * NDCH + c)) * 512 + d;
        n0a[idx] = n0;
        n0 = fma(Dend[idx], n0, nend[idx]);
    }
    nfO[(size_t)b * 512 + d] = (float)n0;
}

// one wave per chunk of 16 steps; lane owns d = 4*lane + j + 256*r
__global__ __launch_bounds__(256)
void denom_kernel(const float* __restrict__ QKV, const float* __restrict__ GG,
                  const double* __restrict__ n0a, float* __restrict__ invd)
{
    const int lane = threadIdx.x & 63;
    const int widx = blockIdx.x * 4 + (threadIdx.x >> 6);
    const int b    = widx >> 6;
    const int c    = widx & 63;
    const int d0   = 4 * lane;

    const float* qb = QKV + (size_t)b * S_ * 1536 + (size_t)c * DCH * 1536;
    const float* gb = GG  + (size_t)b * S_ * 1536 + (size_t)c * DCH * 1536;
    const double* sp = n0a + (size_t)widx * 512;

    double n[2][4];
#pragma unroll
    for (int r = 0; r < 2; ++r) {
        double2 a = *(const double2*)(sp + d0 + 256 * r);
        double2 bb = *(const double2*)(sp + d0 + 256 * r + 2);
        n[r][0] = a.x; n[r][1] = a.y; n[r][2] = bb.x; n[r][3] = bb.y;
    }

    for (int t0 = 0; t0 < DCH; t0 += 4) {
        double dq[4];
#pragma unroll
        for (int i = 0; i < 4; ++i) {
            const float* qr = qb + (size_t)(t0 + i) * 1536;
            const float* gr = gb + (size_t)(t0 + i) * 1536;
            double acc = 0.0;
#pragma unroll
            for (int r = 0; r < 2; ++r) {
                float4 qf = *(const float4*)(qr + d0 + 256 * r);
                float4 kf = *(const float4*)(gr + d0 + 256 * r);
                float4 ff = *(const float4*)(gr + 512 + d0 + 256 * r);
                const float* qp = (const float*)&qf;
                const float* kp = (const float*)&kf;
                const float* fp = (const float*)&ff;
#pragma unroll
                for (int j = 0; j < 4; ++j) {
                    n[r][j] = fma((double)fp[j], n[r][j], (double)kp[j]);
                    acc = fma((double)qp[j], n[r][j], acc);
                }
            }
            dq[i] = acc;
        }
        double u0 = dq[0] + __shfl_xor(dq[0], 32);
        double u1 = dq[1] + __shfl_xor(dq[1], 32);
        double u2 = dq[2] + __shfl_xor(dq[2], 32);
        double u3 = dq[3] + __shfl_xor(dq[3], 32);
        double w0 = (lane & 32) ? u2 : u0;
        double w1 = (lane & 32) ? u3 : u1;
        w0 += __shfl_xor(w0, 16);
        w1 += __shfl_xor(w1, 16);
        double y = (lane & 16) ? w1 : w0;
        y += __shfl_xor(y, 8); y += __shfl_xor(y, 4);
        y += __shfl_xor(y, 2); y += __shfl_xor(y, 1);
        if ((lane & 15) == 0) {
            const int g = lane >> 4;
            const double den = (y > 1e-6) ? y : 1e-6;
            invd[(size_t)b * S_ + c * DCH + t0 + g] = (float)(1.0 / den);
        }
    }
}

// ---------------------------------------------------------------------------
// Recurrent scan, LDS-shared streams.
// grid = 256 blocks (b = bid&7 -> XCD-local), 4 waves/block.
// Block covers 16 e-cols; wave owns 4 (ew..ew+3), all 512 d
// (lane: d = 4*lane + j + 256*r -> 8 d-elems, C = 32 VGPR).
// q/ik/f staged per T=4 window into LDS ONCE per block (4x less L2 traffic
// than per-wave loads); double-buffered, 1 barrier/window.
// 16 dots/window reduced in one batched 6-shuffle fold chain.
// ---------------------------------------------------------------------------
__global__ __launch_bounds__(256)
void scan_kernel(const float* __restrict__ QKV, const float* __restrict__ GG,
                 const float* __restrict__ invd,
                 float* __restrict__ hs, float* __restrict__ CfO,
                 float* __restrict__ hlO)
{
    const int tid  = threadIdx.x;
    const int lane = tid & 63;
    const int wv   = tid >> 6;
    const int bid  = blockIdx.x;
    const int b    = bid & 7;
    const int e00  = (bid >> 3) * 16;
    const int ew   = e00 + wv * 4;
    const int d0   = 4 * lane;            // float offset in 256-block

    const float* qb  = QKV + (size_t)b * S_ * 1536;
    const float* gb  = GG  + (size_t)b * S_ * 1536;
    const float* ivb = invd + (size_t)b * S_;

    // LDS: [buf][step][ q(512) | ik(512) | f(512) ]
    __shared__ float sD[2][4][1536];
    __shared__ float sVO[2][2][4][16];     // [buf][v/o][step][col]
    __shared__ float sIv[2][4];

    float4 C[2][4];                        // [r][dj] -> 4 e-cols each
#pragma unroll
    for (int r = 0; r < 2; ++r)
#pragma unroll
        for (int j = 0; j < 4; ++j) C[r][j] = make_float4(0.f, 0.f, 0.f, 0.f);

    // staging registers
    float4 rA[4], rB[4];
    float rv = 0.f, ro = 0.f, riv = 0.f;
    const int  fa  = tid;                  // float4 slot 0..255
    const bool loB = (tid < 128);
    const int  u   = tid - 192;            // wave 3 aux loader
    const int  ui  = (u >> 4) & 3, uc = u & 15;

    auto ISSUE = [&](int tw) {
#pragma unroll
        for (int i = 0; i < 4; ++i) {
            const float* qr = qb + (size_t)(tw + i) * 1536;
            const float* gr = gb + (size_t)(tw + i) * 1536;
            rA[i] = (fa < 128) ? *(const float4*)(qr + fa * 4)
                               : *(const float4*)(gr + (fa - 128) * 4);
            if (loB) rB[i] = *(const float4*)(gr + (128 + tid) * 4);
        }
        if (wv == 3) {
            rv = qb[(size_t)(tw + ui) * 1536 + 1024 + e00 + uc];
            ro = gb[(size_t)(tw + ui) * 1536 + 1024 + e00 + uc];
            if (u < 4) riv = ivb[tw + u];
        }
    };
    auto WRITE = [&](int nb) {
#pragma unroll
        for (int i = 0; i < 4; ++i) {
            *(float4*)&sD[nb][i][fa * 4] = rA[i];
            if (loB) *(float4*)&sD[nb][i][(256 + tid) * 4] = rB[i];
        }
        if (wv == 3) {
            sVO[nb][0][ui][uc] = rv;
            sVO[nb][1][ui][uc] = ro;
            if (u < 4) sIv[nb][u] = riv;
        }
    };

    int buf = 0;
    ISSUE(0);
    WRITE(0);
    __syncthreads();

    for (int t0 = 0; t0 < S_; t0 += 4) {
        const bool nxt = (t0 + 4 < S_);
        if (nxt) ISSUE(t0 + 4);            // global loads hide under compute

        float p[16];
#pragma unroll
        for (int m = 0; m < 16; ++m) p[m] = 0.f;

#pragma unroll
        for (int i = 0; i < 4; ++i) {
            const float* row = &sD[buf][i][0];
            float4 q0 = *(const float4*)(row + d0);
            float4 q1 = *(const float4*)(row + 256 + d0);
            float4 k0 = *(const float4*)(row + 512 + d0);
            float4 k1 = *(const float4*)(row + 768 + d0);
            float4 f0 = *(const float4*)(row + 1024 + d0);
            float4 f1 = *(const float4*)(row + 1280 + d0);
            float4 v4 = *(const float4*)&sVO[buf][0][i][wv * 4];
#pragma unroll
            for (int r = 0; r < 2; ++r) {
                const float* qp = (const float*)(r ? &q1 : &q0);
                const float* kp = (const float*)(r ? &k1 : &k0);
                const float* fp = (const float*)(r ? &f1 : &f0);
#pragma unroll
                for (int j = 0; j < 4; ++j) {
                    const float ks = kp[j], fs = fp[j], qs = qp[j];
                    C[r][j].x = fmaf(fs, C[r][j].x, ks * v4.x);
                    C[r][j].y = fmaf(fs, C[r][j].y, ks * v4.y);
                    C[r][j].z = fmaf(fs, C[r][j].z, ks * v4.z);
                    C[r][j].w = fmaf(fs, C[r][j].w, ks * v4.w);
                    p[i * 4 + 0] = fmaf(qs, C[r][j].x, p[i * 4 + 0]);
                    p[i * 4 + 1] = fmaf(qs, C[r][j].y, p[i * 4 + 1]);
                    p[i * 4 + 2] = fmaf(qs, C[r][j].z, p[i * 4 + 2]);
                    p[i * 4 + 3] = fmaf(qs, C[r][j].w, p[i * 4 + 3]);
                }
            }
        }

        // batched fold-reduce: 16 sums over 64 lanes, one 6-shuffle chain
        float u16[16];
#pragma unroll
        for (int m = 0; m < 16; ++m) u16[m] = p[m] + __shfl_xor(p[m], 32);
        float w8[8];
#pragma unroll
        for (int m = 0; m < 8; ++m) {
            float t = (lane & 32) ? u16[m + 8] : u16[m];
            w8[m] = t + __shfl_xor(t, 16);
        }
        float x4[4];
#pragma unroll
        for (int m = 0; m < 4; ++m) {
            float t = (lane & 16) ? w8[m + 4] : w8[m];
            x4[m] = t + __shfl_xor(t, 8);
        }
        float y2[2];
#pragma unroll
        for (int m = 0; m < 2; ++m) {
            float t = (lane & 8) ? x4[m + 2] : x4[m];
            y2[m] = t + __shfl_xor(t, 4);
        }
        float z = (lane & 4) ? y2[1] : y2[0];
        z += __shfl_xor(z, 2);
        z += __shfl_xor(z, 1);
        // lane 4V holds value V = i*4 + c  (V = (lane>>2)&15)

        if ((lane & 3) == 0) {
            const int V = (lane >> 2) & 15;
            const int i = V >> 2, c = V & 3;
            const float h = sVO[buf][1][i][wv * 4 + c] * z * sIv[buf][i];
            hs[((size_t)(b * S_ + t0 + i)) * 512 + ew + c] = h;
            if (t0 + i == S_ - 1) hlO[(size_t)b * 512 + ew + c] = h;
        }

        if (nxt) {
            WRITE(buf ^ 1);
            __syncthreads();
            buf ^= 1;
        }
    }

    // final C
#pragma unroll
    for (int r = 0; r < 2; ++r)
#pragma unroll
        for (int j = 0; j < 4; ++j) {
            const int d = 256 * r + d0 + j;
            *(float4*)&CfO[((size_t)b * 512 + d) * 512 + ew] = C[r][j];
        }
}

// ---------------------------------------------------------------------------
extern "C" void kernel_launch(void* const* d_in, const int* in_sizes, int n_in,
                              void* d_out, int out_size, void* d_ws, size_t ws_size,
                              hipStream_t stream)
{
    const float* x    = (const float*)d_in[0];
    const float* W_in = (const float*)d_in[1];
    const float* b_in = (const float*)d_in[2];
    const float* W_ig = (const float*)d_in[3];
    const float* b_ig = (const float*)d_in[4];
    const float* W_fg = (const float*)d_in[5];
    const float* b_fg = (const float*)d_in[6];
    const float* W_og = (const float*)d_in[7];
    const float* b_og = (const float*)d_in[8];
    const float* W_out= (const float*)d_in[9];
    const float* b_out= (const float*)d_in[10];

    float* out   = (float*)d_out;                       // [8,1024,512]
    float* CfO   = out + (size_t)8 * 1024 * 512;        // [8,512,512]
    float* nfO   = CfO + (size_t)8 * 512 * 512;         // [8,512]
    float* hlO   = nfO + (size_t)8 * 512;               // [8,512]

    float* qkv = (float*)d_ws;                          // [8192,1536] q|k|v
    float* gg  = qkv + (size_t)8192 * 1536;             // [8192,1536] ik|f|o
    float* hsb = gg  + (size_t)8192 * 1536;             // [8192,512]
    // transient n-scan scratch overlaid on hsb (dead before scan_kernel writes)
    double* nend = (double*)hsb;                        // [512][512] f64 (2MB)
    double* Dend = nend + (size_t)8 * NDCH * 512;
    double* n0a  = Dend + (size_t)8 * NDCH * 512;
    float*  invd = hsb + (size_t)8192 * 512;            // [8,1024]

    // 1. proj + tanh(q,k)
    gemm_act<0><<<dim3(12, 64), 256, 0, stream>>>(
        x, 512, W_in, W_in, W_in, b_in, b_in, b_in, qkv, 1536);
    // 2. gates: [i*k | f | o]
    gemm_act<1><<<dim3(12, 64), 256, 0, stream>>>(
        qkv + 1024, 1536, W_ig, W_fg, W_og, b_ig, b_fg, b_og, gg, 1536);
    // 3. n-scan + denominators (f64)
    nscan_local <<<512, 512, 0, stream>>>(gg, nend, Dend);
    nscan_stitch<<<  8, 512, 0, stream>>>(nend, Dend, n0a, nfO);
    denom_kernel<<<128, 256, 0, stream>>>(qkv, gg, n0a, invd);
    // 4. recurrent scan (C only), LDS-shared streams
    scan_kernel<<<256, 256, 0, stream>>>(qkv, gg, invd, hsb, CfO, hlO);
    // 5. out = hs @ W_out + b_out
    gemm_act<2><<<dim3(4, 64), 256, 0, stream>>>(
        hsb, 512, W_out, W_out, W_out, b_out, b_out, b_out, out, 512);
}

// Round 6
// 1029.098 us; speedup vs baseline: 1.3111x; 1.3111x over previous
//
#include <hip/hip_runtime.h>

#define S_ 1024
#define D_ 512
#define DCH 16      // denom chunk length (f64 pipeline)
#define NDCH 64     // denom chunks per batch
#define CT 32       // GEMM-scan chunk length
#define NCT 32      // GEMM-scan chunks per batch

// ---------------------------------------------------------------------------
// GEMM + bias + activation.  C[m,n] = act(sum_k A[m,k]*B[k,n] + bias[n])
// MODE 0: proj   A=x   (lda 512),  B=W_in (ldb 2048), N=1536, tanh for n<1024
// MODE 1: gates  A=v   (lda 1536), B=W_ig/W_fg/W_og (ldb 512), sigmoid;
//                g==0 (i-gate) fused to i*k (k read from qkv).
// MODE 2: out    A=hs  (lda 512),  B=W_out (ldb 512), N=512, no act
// ---------------------------------------------------------------------------
template<int MODE>
__global__ __launch_bounds__(256)
void gemm_act(const float* __restrict__ A, int lda,
              const float* __restrict__ W0, const float* __restrict__ W1,
              const float* __restrict__ W2,
              const float* __restrict__ bb0, const float* __restrict__ bb1,
              const float* __restrict__ bb2,
              float* __restrict__ Co, int ldc)
{
    const int tid = threadIdx.x;
    const int n0  = blockIdx.x * 128;
    const int m0  = blockIdx.y * 128;

    const float* Bp; const float* bias; int ldb;
    if (MODE == 1) {
        const int g  = n0 >> 9;
        const int nn = n0 & 511;
        Bp   = (g == 0 ? W0 : g == 1 ? W1 : W2) + nn;
        bias = (g == 0 ? bb0 : g == 1 ? bb1 : bb2) + nn;
        ldb  = 512;
    } else {
        Bp   = W0 + n0;
        bias = bb0 + n0;
        ldb  = (MODE == 0 ? 2048 : 512);
    }

    __shared__ float As[16][128];   // K-major
    __shared__ float Bs[16][128];

    float acc[8][8];
#pragma unroll
    for (int i = 0; i < 8; ++i)
#pragma unroll
        for (int j = 0; j < 8; ++j) acc[i][j] = 0.f;

    const int ar = tid >> 2;
    const int ac = (tid & 3) * 4;
    const int br = tid >> 5;
    const int bc = (tid & 31) * 4;
    const int ty = tid >> 4;
    const int tx = tid & 15;

    const float* Ap = A + (size_t)(m0 + ar) * lda + ac;
    const float* Bq = Bp + (size_t)br * ldb + bc;

    for (int k0 = 0; k0 < 512; k0 += 16) {
        float4 a0 = *(const float4*)(Ap);
        float4 a1 = *(const float4*)(Ap + (size_t)64 * lda);
        float4 b0 = *(const float4*)(Bq);
        float4 b1 = *(const float4*)(Bq + (size_t)8 * ldb);
        Ap += 16; Bq += (size_t)16 * ldb;

        __syncthreads();
        As[ac + 0][ar]      = a0.x; As[ac + 1][ar]      = a0.y;
        As[ac + 2][ar]      = a0.z; As[ac + 3][ar]      = a0.w;
        As[ac + 0][ar + 64] = a1.x; As[ac + 1][ar + 64] = a1.y;
        As[ac + 2][ar + 64] = a1.z; As[ac + 3][ar + 64] = a1.w;
        *(float4*)&Bs[br][bc]     = b0;
        *(float4*)&Bs[br + 8][bc] = b1;
        __syncthreads();

#pragma unroll
        for (int kk = 0; kk < 16; ++kk) {
            float4 aL = *(const float4*)&As[kk][ty * 4];
            float4 aH = *(const float4*)&As[kk][64 + ty * 4];
            float4 bL = *(const float4*)&Bs[kk][tx * 4];
            float4 bH = *(const float4*)&Bs[kk][64 + tx * 4];
            float av[8] = {aL.x, aL.y, aL.z, aL.w, aH.x, aH.y, aH.z, aH.w};
            float bv[8] = {bL.x, bL.y, bL.z, bL.w, bH.x, bH.y, bH.z, bH.w};
#pragma unroll
            for (int i = 0; i < 8; ++i)
#pragma unroll
                for (int j = 0; j < 8; ++j)
                    acc[i][j] = fmaf(av[i], bv[j], acc[i][j]);
        }
    }

    float bv[8];
#pragma unroll
    for (int j = 0; j < 8; ++j) {
        const int c = (j < 4) ? (tx * 4 + j) : (64 + tx * 4 + j - 4);
        bv[j] = bias[c];
    }
#pragma unroll
    for (int i = 0; i < 8; ++i) {
        const int m = m0 + ((i < 4) ? (ty * 4 + i) : (64 + ty * 4 + i - 4));
        float vals[8];
#pragma unroll
        for (int j = 0; j < 8; ++j) {
            float v = acc[i][j] + bv[j];
            if (MODE == 0) {
                const int cg = n0 + ((j < 4) ? (tx * 4 + j) : (64 + tx * 4 + j - 4));
                if (cg < 1024) v = tanhf(v);
            } else if (MODE == 1) {
                v = 1.0f / (1.0f + expf(-v));
            }
            vals[j] = v;
        }
        if (MODE == 1 && n0 < 512) {
            const float* krow = A + (size_t)m * lda - 512;
            float4 kl = *(const float4*)(krow + n0 + tx * 4);
            float4 kh = *(const float4*)(krow + n0 + 64 + tx * 4);
            vals[0] *= kl.x; vals[1] *= kl.y; vals[2] *= kl.z; vals[3] *= kl.w;
            vals[4] *= kh.x; vals[5] *= kh.y; vals[6] *= kh.z; vals[7] *= kh.w;
        }
        float* row = Co + (size_t)m * ldc + n0;
        *(float4*)&row[tx * 4]      = make_float4(vals[0], vals[1], vals[2], vals[3]);
        *(float4*)&row[64 + tx * 4] = make_float4(vals[4], vals[5], vals[6], vals[7]);
    }
}

// ---------------------------------------------------------------------------
// f64 denominator pipeline (unchanged from R4 — needed because den is clamped
// at 1e-6 and amplifies absolute error by ~1e6; f32 dots are NOT enough).
// Runs on ORIGINAL q/ik/f, i.e. before chunk_prep overwrites them.
// ---------------------------------------------------------------------------
__global__ __launch_bounds__(512)
void nscan_local(const float* __restrict__ GG,
                 double* __restrict__ nend, double* __restrict__ Dend)
{
    const int b = blockIdx.x >> 6;
    const int c = blockIdx.x & 63;
    const int d = threadIdx.x;
    const float* gb = GG + (size_t)b * S_ * 1536 + (size_t)c * DCH * 1536;
    double n = 0.0, P = 1.0;
    for (int u = 0; u < DCH; ++u) {
        const float* row = gb + (size_t)u * 1536;
        const double ik = (double)row[d];
        const double f  = (double)row[512 + d];
        n = fma(f, n, ik);
        P *= f;
    }
    nend[(size_t)blockIdx.x * 512 + d] = n;
    Dend[(size_t)blockIdx.x * 512 + d] = P;
}

__global__ __launch_bounds__(512)
void nscan_stitch(const double* __restrict__ nend, const double* __restrict__ Dend,
                  double* __restrict__ n0a, float* __restrict__ nfO)
{
    const int b = blockIdx.x;
    const int d = threadIdx.x;
    double n0 = 0.0;
    for (int c = 0; c < NDCH; ++c) {
        const size_t idx = ((size_t)(b * NDCH + c)) * 512 + d;
        n0a[idx] = n0;
        n0 = fma(Dend[idx], n0, nend[idx]);
    }
    nfO[(size_t)b * 512 + d] = (float)n0;
}

__global__ __launch_bounds__(256)
void denom_kernel(const float* __restrict__ QKV, const float* __restrict__ GG,
                  const double* __restrict__ n0a, float* __restrict__ invd)
{
    const int lane = threadIdx.x & 63;
    const int widx = blockIdx.x * 4 + (threadIdx.x >> 6);
    const int b    = widx >> 6;
    const int c    = widx & 63;
    const int d0   = 4 * lane;

    const float* qb = QKV + (size_t)b * S_ * 1536 + (size_t)c * DCH * 1536;
    const float* gb = GG  + (size_t)b * S_ * 1536 + (size_t)c * DCH * 1536;
    const double* sp = n0a + (size_t)widx * 512;

    double n[2][4];
#pragma unroll
    for (int r = 0; r < 2; ++r) {
        double2 a = *(const double2*)(sp + d0 + 256 * r);
        double2 bb = *(const double2*)(sp + d0 + 256 * r + 2);
        n[r][0] = a.x; n[r][1] = a.y; n[r][2] = bb.x; n[r][3] = bb.y;
    }

    for (int t0 = 0; t0 < DCH; t0 += 4) {
        double dq[4];
#pragma unroll
        for (int i = 0; i < 4; ++i) {
            const float* qr = qb + (size_t)(t0 + i) * 1536;
            const float* gr = gb + (size_t)(t0 + i) * 1536;
            double acc = 0.0;
#pragma unroll
            for (int r = 0; r < 2; ++r) {
                float4 qf = *(const float4*)(qr + d0 + 256 * r);
                float4 kf = *(const float4*)(gr + d0 + 256 * r);
                float4 ff = *(const float4*)(gr + 512 + d0 + 256 * r);
                const float* qp = (const float*)&qf;
                const float* kp = (const float*)&kf;
                const float* fp = (const float*)&ff;
#pragma unroll
                for (int j = 0; j < 4; ++j) {
                    n[r][j] = fma((double)fp[j], n[r][j], (double)kp[j]);
                    acc = fma((double)qp[j], n[r][j], acc);
                }
            }
            dq[i] = acc;
        }
        double u0 = dq[0] + __shfl_xor(dq[0], 32);
        double u1 = dq[1] + __shfl_xor(dq[1], 32);
        double u2 = dq[2] + __shfl_xor(dq[2], 32);
        double u3 = dq[3] + __shfl_xor(dq[3], 32);
        double w0 = (lane & 32) ? u2 : u0;
        double w1 = (lane & 32) ? u3 : u1;
        w0 += __shfl_xor(w0, 16);
        w1 += __shfl_xor(w1, 16);
        double y = (lane & 16) ? w1 : w0;
        y += __shfl_xor(y, 8); y += __shfl_xor(y, 4);
        y += __shfl_xor(y, 2); y += __shfl_xor(y, 1);
        if ((lane & 15) == 0) {
            const int g = lane >> 4;
            const double den = (y > 1e-6) ? y : 1e-6;
            invd[(size_t)b * S_ + c * DCH + t0 + g] = (float)(1.0 / den);
        }
    }
}

// ---------------------------------------------------------------------------
// chunk_prep: per (b, chunk of 32, d): F cumprod; q -> q*F (in place),
// ik -> ik/F (in place), F_T stored into the (now dead) f-slot of the
// chunk's FIRST row:  gg[row(t0)*1536 + 512 + d].
// ---------------------------------------------------------------------------
__global__ __launch_bounds__(512)
void chunk_prep(float* __restrict__ qkv, float* __restrict__ gg)
{
    const int b = blockIdx.x >> 5;
    const int c = blockIdx.x & 31;
    const int d = threadIdx.x;
    float* qr = qkv + ((size_t)(b * S_ + c * CT)) * 1536 + d;
    float* gr = gg  + ((size_t)(b * S_ + c * CT)) * 1536 + d;
    float* ft = gr + 512;                 // f-slot of first chunk row
    float F = 1.f;
    for (int u = 0; u < CT; ++u) {
        const float q = qr[0], ik = gr[0], f = gr[512];
        F *= f;
        qr[0] = q * F;
        gr[0] = ik / F;
        qr += 1536; gr += 1536;
    }
    ft[0] = F;                            // written after all f reads of row t0
}

// ---------------------------------------------------------------------------
// chunk_A: per (b, chunk): A[t,s] = sum_d qt[t,d]*kt[s,d] (s<=t, else 0),
// then H1[t,e] = sum_s A[t,s] * v[s,e]  -> hsb.   Fully chunk-parallel.
// ---------------------------------------------------------------------------
__global__ __launch_bounds__(256)
void chunk_A(const float* __restrict__ qkv, const float* __restrict__ gg,
             float* __restrict__ h1out)
{
    const int b   = blockIdx.x >> 5;
    const int c   = blockIdx.x & 31;
    const int tid = threadIdx.x;
    const int t   = tid & 31;
    const int g   = tid >> 5;             // 0..7

    __shared__ float sA[32][33];

    const size_t rb = (size_t)(b * S_ + c * CT);
    const float* qr = qkv + (rb + t) * 1536;            // qt row t
    const float* kb = gg + rb * 1536;                    // kt rows

    // ---- dots: thread computes A[t, 4g .. 4g+3] over d=512 ----
    {
        const int s0 = g * 4;
        const float* k0 = kb + (size_t)(s0 + 0) * 1536;
        const float* k1 = kb + (size_t)(s0 + 1) * 1536;
        const float* k2 = kb + (size_t)(s0 + 2) * 1536;
        const float* k3 = kb + (size_t)(s0 + 3) * 1536;
        float a0 = 0.f, a1 = 0.f, a2 = 0.f, a3 = 0.f;
        for (int d4 = 0; d4 < 512; d4 += 4) {
            float4 qv = *(const float4*)(qr + d4);
            float4 x0 = *(const float4*)(k0 + d4);
            float4 x1 = *(const float4*)(k1 + d4);
            float4 x2 = *(const float4*)(k2 + d4);
            float4 x3 = *(const float4*)(k3 + d4);
            a0 = fmaf(qv.x, x0.x, a0); a0 = fmaf(qv.y, x0.y, a0);
            a0 = fmaf(qv.z, x0.z, a0); a0 = fmaf(qv.w, x0.w, a0);
            a1 = fmaf(qv.x, x1.x, a1); a1 = fmaf(qv.y, x1.y, a1);
            a1 = fmaf(qv.z, x1.z, a1); a1 = fmaf(qv.w, x1.w, a1);
            a2 = fmaf(qv.x, x2.x, a2); a2 = fmaf(qv.y, x2.y, a2);
            a2 = fmaf(qv.z, x2.z, a2); a2 = fmaf(qv.w, x2.w, a2);
            a3 = fmaf(qv.x, x3.x, a3); a3 = fmaf(qv.y, x3.y, a3);
            a3 = fmaf(qv.z, x3.z, a3); a3 = fmaf(qv.w, x3.w, a3);
        }
        sA[t][s0 + 0] = (s0 + 0 <= t) ? a0 : 0.f;
        sA[t][s0 + 1] = (s0 + 1 <= t) ? a1 : 0.f;
        sA[t][s0 + 2] = (s0 + 2 <= t) ? a2 : 0.f;
        sA[t][s0 + 3] = (s0 + 3 <= t) ? a3 : 0.f;
    }
    __syncthreads();

    // ---- H1: thread computes h1[t][64g .. 64g+63] ----
    {
        const int e0 = g * 64;
        float4 h[16];
#pragma unroll
        for (int m = 0; m < 16; ++m) h[m] = make_float4(0.f, 0.f, 0.f, 0.f);
        const float* vb = qkv + rb * 1536 + 1024 + e0;
        for (int s = 0; s < CT; ++s) {
            const float a = sA[t][s];
            const float* vr = vb + (size_t)s * 1536;
#pragma unroll
            for (int m = 0; m < 16; ++m) {
                float4 vv = *(const float4*)(vr + m * 4);
                h[m].x = fmaf(a, vv.x, h[m].x);
                h[m].y = fmaf(a, vv.y, h[m].y);
                h[m].z = fmaf(a, vv.z, h[m].z);
                h[m].w = fmaf(a, vv.w, h[m].w);
            }
        }
        float* orow = h1out + (rb + t) * 512 + e0;
#pragma unroll
        for (int m = 0; m < 16; ++m) *(float4*)(orow + m * 4) = h[m];
    }
}

// ---------------------------------------------------------------------------
// chunk_scan: the only sequential part.  grid 256 = 8 batches x 32 e-blocks,
// 4 waves/block, wave owns 4 e-cols x all 512 d (lane: d = 4*lane+j+256r).
// Per chunk: 32 steps of {H2 partial dot vs frozen C; Cacc += kt (x) v},
// then C = F_T o (C + Cacc).  Dots reduced in 4 batched folds of 32.
// No LDS, no barriers.  h = (H2 + H1)*o*invd written in place over H1 (hsb).
// ---------------------------------------------------------------------------
__global__ __launch_bounds__(256)
void chunk_scan(const float* __restrict__ qkv, const float* __restrict__ gg,
                const float* __restrict__ invd,
                float* __restrict__ hs, float* __restrict__ CfO,
                float* __restrict__ hlO)
{
    const int tid  = threadIdx.x;
    const int lane = tid & 63;
    const int wv   = tid >> 6;
    const int b    = blockIdx.x & 7;
    const int ew   = (blockIdx.x >> 3) * 16 + wv * 4;
    const int d0   = 4 * lane;

    const float* qb  = qkv + (size_t)b * S_ * 1536;
    const float* gb  = gg  + (size_t)b * S_ * 1536;
    const float* ivb = invd + (size_t)b * S_;

    float4 C[2][4];
#pragma unroll
    for (int r = 0; r < 2; ++r)
#pragma unroll
        for (int j = 0; j < 4; ++j) C[r][j] = make_float4(0.f, 0.f, 0.f, 0.f);

    for (int c = 0; c < NCT; ++c) {
        const int t0 = c * CT;
        float4 Cacc[2][4];
#pragma unroll
        for (int r = 0; r < 2; ++r)
#pragma unroll
            for (int j = 0; j < 4; ++j) Cacc[r][j] = make_float4(0.f, 0.f, 0.f, 0.f);

        for (int sb = 0; sb < 4; ++sb) {
            float p[32];
#pragma unroll
            for (int m = 0; m < 32; ++m) p[m] = 0.f;

#pragma unroll
            for (int uu = 0; uu < 8; ++uu) {
                const int u = t0 + sb * 8 + uu;
                const float* qr = qb + (size_t)u * 1536;
                const float* gr = gb + (size_t)u * 1536;
                float4 q0 = *(const float4*)(qr + d0);
                float4 q1 = *(const float4*)(qr + 256 + d0);
                float4 k0 = *(const float4*)(gr + d0);
                float4 k1 = *(const float4*)(gr + 256 + d0);
                float4 v4 = *(const float4*)(qr + 1024 + ew);

                float px = 0.f, py = 0.f, pz = 0.f, pw = 0.f;
                const float* q0p = (const float*)&q0;
                const float* q1p = (const float*)&q1;
                const float* k0p = (const float*)&k0;
                const float* k1p = (const float*)&k1;
#pragma unroll
                for (int j = 0; j < 4; ++j) {
                    const float qa = q0p[j], qc = q1p[j];
                    px = fmaf(qa, C[0][j].x, px); px = fmaf(qc, C[1][j].x, px);
                    py = fmaf(qa, C[0][j].y, py); py = fmaf(qc, C[1][j].y, py);
                    pz = fmaf(qa, C[0][j].z, pz); pz = fmaf(qc, C[1][j].z, pz);
                    pw = fmaf(qa, C[0][j].w, pw); pw = fmaf(qc, C[1][j].w, pw);
                    const float ka = k0p[j], kc = k1p[j];
                    Cacc[0][j].x = fmaf(ka, v4.x, Cacc[0][j].x);
                    Cacc[0][j].y = fmaf(ka, v4.y, Cacc[0][j].y);
                    Cacc[0][j].z = fmaf(ka, v4.z, Cacc[0][j].z);
                    Cacc[0][j].w = fmaf(ka, v4.w, Cacc[0][j].w);
                    Cacc[1][j].x = fmaf(kc, v4.x, Cacc[1][j].x);
                    Cacc[1][j].y = fmaf(kc, v4.y, Cacc[1][j].y);
                    Cacc[1][j].z = fmaf(kc, v4.z, Cacc[1][j].z);
                    Cacc[1][j].w = fmaf(kc, v4.w, Cacc[1][j].w);
                }
                p[uu * 4 + 0] = px; p[uu * 4 + 1] = py;
                p[uu * 4 + 2] = pz; p[uu * 4 + 3] = pw;
            }

            // batched fold: 32 sums over 64 lanes; even lane L holds m=(L>>1)&31
#pragma unroll
            for (int m = 0; m < 32; ++m) p[m] += __shfl_xor(p[m], 32);
#pragma unroll
            for (int m = 0; m < 16; ++m) {
                float t = (lane & 32) ? p[m + 16] : p[m];
                p[m] = t + __shfl_xor(t, 16);
            }
#pragma unroll
            for (int m = 0; m < 8; ++m) {
                float t = (lane & 16) ? p[m + 8] : p[m];
                p[m] = t + __shfl_xor(t, 8);
            }
#pragma unroll
            for (int m = 0; m < 4; ++m) {
                float t = (lane & 8) ? p[m + 4] : p[m];
                p[m] = t + __shfl_xor(t, 4);
            }
#pragma unroll
            for (int m = 0; m < 2; ++m) {
                float t = (lane & 4) ? p[m + 2] : p[m];
                p[m] = t + __shfl_xor(t, 2);
            }
            float z;
            {
                float t = (lane & 2) ? p[1] : p[0];
                z = t + __shfl_xor(t, 1);
            }

            if ((lane & 1) == 0) {
                const int m  = (lane >> 1) & 31;
                const int tg = t0 + sb * 8 + (m >> 2);
                const int e  = ew + (m & 3);
                const size_t row = (size_t)(b * S_ + tg);
                const float h1 = hs[row * 512 + e];
                const float oe = gb[(size_t)tg * 1536 + 1024 + e];
                const float h  = (z + h1) * oe * ivb[tg];
                hs[row * 512 + e] = h;
                if (tg == S_ - 1) hlO[(size_t)b * 512 + e] = h;
            }
        }

        // C = F_T o (C + Cacc);  F_T lives in f-slot of chunk's first row
        const float* ftp = gb + (size_t)t0 * 1536 + 512;
        float4 F0 = *(const float4*)(ftp + d0);
        float4 F1 = *(const float4*)(ftp + 256 + d0);
        const float* f0p = (const float*)&F0;
        const float* f1p = (const float*)&F1;
#pragma unroll
        for (int j = 0; j < 4; ++j) {
            C[0][j].x = f0p[j] * (C[0][j].x + Cacc[0][j].x);
            C[0][j].y = f0p[j] * (C[0][j].y + Cacc[0][j].y);
            C[0][j].z = f0p[j] * (C[0][j].z + Cacc[0][j].z);
            C[0][j].w = f0p[j] * (C[0][j].w + Cacc[0][j].w);
            C[1][j].x = f1p[j] * (C[1][j].x + Cacc[1][j].x);
            C[1][j].y = f1p[j] * (C[1][j].y + Cacc[1][j].y);
            C[1][j].z = f1p[j] * (C[1][j].z + Cacc[1][j].z);
            C[1][j].w = f1p[j] * (C[1][j].w + Cacc[1][j].w);
        }
    }

    // final C
#pragma unroll
    for (int r = 0; r < 2; ++r)
#pragma unroll
        for (int j = 0; j < 4; ++j) {
            const int d = 256 * r + d0 + j;
            *(float4*)&CfO[((size_t)b * 512 + d) * 512 + ew] = C[r][j];
        }
}

// ---------------------------------------------------------------------------
extern "C" void kernel_launch(void* const* d_in, const int* in_sizes, int n_in,
                              void* d_out, int out_size, void* d_ws, size_t ws_size,
                              hipStream_t stream)
{
    const float* x    = (const float*)d_in[0];
    const float* W_in = (const float*)d_in[1];
    const float* b_in = (const float*)d_in[2];
    const float* W_ig = (const float*)d_in[3];
    const float* b_ig = (const float*)d_in[4];
    const float* W_fg = (const float*)d_in[5];
    const float* b_fg = (const float*)d_in[6];
    const float* W_og = (const float*)d_in[7];
    const float* b_og = (const float*)d_in[8];
    const float* W_out= (const float*)d_in[9];
    const float* b_out= (const float*)d_in[10];

    float* out   = (float*)d_out;                       // [8,1024,512]
    float* CfO   = out + (size_t)8 * 1024 * 512;        // [8,512,512]
    float* nfO   = CfO + (size_t)8 * 512 * 512;         // [8,512]
    float* hlO   = nfO + (size_t)8 * 512;               // [8,512]

    float* qkv = (float*)d_ws;                          // [8192,1536] q|k|v -> qt|k|v
    float* gg  = qkv + (size_t)8192 * 1536;             // [8192,1536] ik|f|o -> kt|f/FT|o
    float* hsb = gg  + (size_t)8192 * 1536;             // [8192,512]  H1 -> h
    // transient f64 n-scan scratch overlaid on hsb (dead before chunk_A writes)
    double* nend = (double*)hsb;
    double* Dend = nend + (size_t)8 * NDCH * 512;
    double* n0a  = Dend + (size_t)8 * NDCH * 512;
    float*  invd = hsb + (size_t)8192 * 512;            // [8,1024]

    // 1. proj + tanh(q,k)
    gemm_act<0><<<dim3(12, 64), 256, 0, stream>>>(
        x, 512, W_in, W_in, W_in, b_in, b_in, b_in, qkv, 1536);
    // 2. gates: [i*k | f | o]
    gemm_act<1><<<dim3(12, 64), 256, 0, stream>>>(
        qkv + 1024, 1536, W_ig, W_fg, W_og, b_ig, b_fg, b_og, gg, 1536);
    // 3. f64 denominators on ORIGINAL q/ik/f
    nscan_local <<<512, 512, 0, stream>>>(gg, nend, Dend);
    nscan_stitch<<<  8, 512, 0, stream>>>(nend, Dend, n0a, nfO);
    denom_kernel<<<128, 256, 0, stream>>>(qkv, gg, n0a, invd);
    // 4. chunk transforms: q->q*F, ik->ik/F, F_T into f-slot of chunk row 0
    chunk_prep<<<256, 512, 0, stream>>>(qkv, gg);
    // 5. intra-chunk attention term: H1 = tril(Qt Kt^T) V  -> hsb
    chunk_A<<<256, 256, 0, stream>>>(qkv, gg, hsb);
    // 6. sequential chunk recurrence (C only) + combine -> hsb final h
    chunk_scan<<<256, 256, 0, stream>>>(qkv, gg, invd, hsb, CfO, hlO);
    // 7. out = hs @ W_out + b_out
    gemm_act<2><<<dim3(4, 64), 256, 0, stream>>>(
        hsb, 512, W_out, W_out, W_out, b_out, b_out, b_out, out, 512);
}

// Round 7
// 813.742 us; speedup vs baseline: 1.6581x; 1.2646x over previous
//
#include <hip/hip_runtime.h>

#define S_ 1024
#define D_ 512
#define DCH 16      // denom chunk length (f64 pipeline)
#define NDCH 64     // denom chunks per batch
#define CT 32       // GEMM-scan chunk length
#define NCT 32      // GEMM-scan chunks per batch

__device__ __forceinline__ unsigned short f2bf(float x) {
    unsigned int u = __float_as_uint(x);
    u = (u + 0x7FFFu + ((u >> 16) & 1u)) >> 16;
    return (unsigned short)u;
}
__device__ __forceinline__ float bf2f(unsigned short s) {
    return __uint_as_float(((unsigned int)s) << 16);
}

// ---------------------------------------------------------------------------
// GEMM + bias + activation (unchanged from R6)
// ---------------------------------------------------------------------------
template<int MODE>
__global__ __launch_bounds__(256)
void gemm_act(const float* __restrict__ A, int lda,
              const float* __restrict__ W0, const float* __restrict__ W1,
              const float* __restrict__ W2,
              const float* __restrict__ bb0, const float* __restrict__ bb1,
              const float* __restrict__ bb2,
              float* __restrict__ Co, int ldc)
{
    const int tid = threadIdx.x;
    const int n0  = blockIdx.x * 128;
    const int m0  = blockIdx.y * 128;

    const float* Bp; const float* bias; int ldb;
    if (MODE == 1) {
        const int g  = n0 >> 9;
        const int nn = n0 & 511;
        Bp   = (g == 0 ? W0 : g == 1 ? W1 : W2) + nn;
        bias = (g == 0 ? bb0 : g == 1 ? bb1 : bb2) + nn;
        ldb  = 512;
    } else {
        Bp   = W0 + n0;
        bias = bb0 + n0;
        ldb  = (MODE == 0 ? 2048 : 512);
    }

    __shared__ float As[16][128];
    __shared__ float Bs[16][128];

    float acc[8][8];
#pragma unroll
    for (int i = 0; i < 8; ++i)
#pragma unroll
        for (int j = 0; j < 8; ++j) acc[i][j] = 0.f;

    const int ar = tid >> 2;
    const int ac = (tid & 3) * 4;
    const int br = tid >> 5;
    const int bc = (tid & 31) * 4;
    const int ty = tid >> 4;
    const int tx = tid & 15;

    const float* Ap = A + (size_t)(m0 + ar) * lda + ac;
    const float* Bq = Bp + (size_t)br * ldb + bc;

    for (int k0 = 0; k0 < 512; k0 += 16) {
        float4 a0 = *(const float4*)(Ap);
        float4 a1 = *(const float4*)(Ap + (size_t)64 * lda);
        float4 b0 = *(const float4*)(Bq);
        float4 b1 = *(const float4*)(Bq + (size_t)8 * ldb);
        Ap += 16; Bq += (size_t)16 * ldb;

        __syncthreads();
        As[ac + 0][ar]      = a0.x; As[ac + 1][ar]      = a0.y;
        As[ac + 2][ar]      = a0.z; As[ac + 3][ar]      = a0.w;
        As[ac + 0][ar + 64] = a1.x; As[ac + 1][ar + 64] = a1.y;
        As[ac + 2][ar + 64] = a1.z; As[ac + 3][ar + 64] = a1.w;
        *(float4*)&Bs[br][bc]     = b0;
        *(float4*)&Bs[br + 8][bc] = b1;
        __syncthreads();

#pragma unroll
        for (int kk = 0; kk < 16; ++kk) {
            float4 aL = *(const float4*)&As[kk][ty * 4];
            float4 aH = *(const float4*)&As[kk][64 + ty * 4];
            float4 bL = *(const float4*)&Bs[kk][tx * 4];
            float4 bH = *(const float4*)&Bs[kk][64 + tx * 4];
            float av[8] = {aL.x, aL.y, aL.z, aL.w, aH.x, aH.y, aH.z, aH.w};
            float bv[8] = {bL.x, bL.y, bL.z, bL.w, bH.x, bH.y, bH.z, bH.w};
#pragma unroll
            for (int i = 0; i < 8; ++i)
#pragma unroll
                for (int j = 0; j < 8; ++j)
                    acc[i][j] = fmaf(av[i], bv[j], acc[i][j]);
        }
    }

    float bv[8];
#pragma unroll
    for (int j = 0; j < 8; ++j) {
        const int c = (j < 4) ? (tx * 4 + j) : (64 + tx * 4 + j - 4);
        bv[j] = bias[c];
    }
#pragma unroll
    for (int i = 0; i < 8; ++i) {
        const int m = m0 + ((i < 4) ? (ty * 4 + i) : (64 + ty * 4 + i - 4));
        float vals[8];
#pragma unroll
        for (int j = 0; j < 8; ++j) {
            float v = acc[i][j] + bv[j];
            if (MODE == 0) {
                const int cg = n0 + ((j < 4) ? (tx * 4 + j) : (64 + tx * 4 + j - 4));
                if (cg < 1024) v = tanhf(v);
            } else if (MODE == 1) {
                v = 1.0f / (1.0f + expf(-v));
            }
            vals[j] = v;
        }
        if (MODE == 1 && n0 < 512) {
            const float* krow = A + (size_t)m * lda - 512;
            float4 kl = *(const float4*)(krow + n0 + tx * 4);
            float4 kh = *(const float4*)(krow + n0 + 64 + tx * 4);
            vals[0] *= kl.x; vals[1] *= kl.y; vals[2] *= kl.z; vals[3] *= kl.w;
            vals[4] *= kh.x; vals[5] *= kh.y; vals[6] *= kh.z; vals[7] *= kh.w;
        }
        float* row = Co + (size_t)m * ldc + n0;
        *(float4*)&row[tx * 4]      = make_float4(vals[0], vals[1], vals[2], vals[3]);
        *(float4*)&row[64 + tx * 4] = make_float4(vals[4], vals[5], vals[6], vals[7]);
    }
}

// ---------------------------------------------------------------------------
// f64 denominator pipeline (unchanged)
// ---------------------------------------------------------------------------
__global__ __launch_bounds__(512)
void nscan_local(const float* __restrict__ GG,
                 double* __restrict__ nend, double* __restrict__ Dend)
{
    const int b = blockIdx.x >> 6;
    const int c = blockIdx.x & 63;
    const int d = threadIdx.x;
    const float* gb = GG + (size_t)b * S_ * 1536 + (size_t)c * DCH * 1536;
    double n = 0.0, P = 1.0;
    for (int u = 0; u < DCH; ++u) {
        const float* row = gb + (size_t)u * 1536;
        const double ik = (double)row[d];
        const double f  = (double)row[512 + d];
        n = fma(f, n, ik);
        P *= f;
    }
    nend[(size_t)blockIdx.x * 512 + d] = n;
    Dend[(size_t)blockIdx.x * 512 + d] = P;
}

__global__ __launch_bounds__(512)
void nscan_stitch(const double* __restrict__ nend, const double* __restrict__ Dend,
                  double* __restrict__ n0a, float* __restrict__ nfO)
{
    const int b = blockIdx.x;
    const int d = threadIdx.x;
    double n0 = 0.0;
    for (int c = 0; c < NDCH; ++c) {
        const size_t idx = ((size_t)(b * NDCH + c)) * 512 + d;
        n0a[idx] = n0;
        n0 = fma(Dend[idx], n0, nend[idx]);
    }
    nfO[(size_t)b * 512 + d] = (float)n0;
}

__global__ __launch_bounds__(256)
void denom_kernel(const float* __restrict__ QKV, const float* __restrict__ GG,
                  const double* __restrict__ n0a, float* __restrict__ invd)
{
    const int lane = threadIdx.x & 63;
    const int widx = blockIdx.x * 4 + (threadIdx.x >> 6);
    const int b    = widx >> 6;
    const int c    = widx & 63;
    const int d0   = 4 * lane;

    const float* qb = QKV + (size_t)b * S_ * 1536 + (size_t)c * DCH * 1536;
    const float* gb = GG  + (size_t)b * S_ * 1536 + (size_t)c * DCH * 1536;
    const double* sp = n0a + (size_t)widx * 512;

    double n[2][4];
#pragma unroll
    for (int r = 0; r < 2; ++r) {
        double2 a = *(const double2*)(sp + d0 + 256 * r);
        double2 bb = *(const double2*)(sp + d0 + 256 * r + 2);
        n[r][0] = a.x; n[r][1] = a.y; n[r][2] = bb.x; n[r][3] = bb.y;
    }

    for (int t0 = 0; t0 < DCH; t0 += 4) {
        double dq[4];
#pragma unroll
        for (int i = 0; i < 4; ++i) {
            const float* qr = qb + (size_t)(t0 + i) * 1536;
            const float* gr = gb + (size_t)(t0 + i) * 1536;
            double acc = 0.0;
#pragma unroll
            for (int r = 0; r < 2; ++r) {
                float4 qf = *(const float4*)(qr + d0 + 256 * r);
                float4 kf = *(const float4*)(gr + d0 + 256 * r);
                float4 ff = *(const float4*)(gr + 512 + d0 + 256 * r);
                const float* qp = (const float*)&qf;
                const float* kp = (const float*)&kf;
                const float* fp = (const float*)&ff;
#pragma unroll
                for (int j = 0; j < 4; ++j) {
                    n[r][j] = fma((double)fp[j], n[r][j], (double)kp[j]);
                    acc = fma((double)qp[j], n[r][j], acc);
                }
            }
            dq[i] = acc;
        }
        double u0 = dq[0] + __shfl_xor(dq[0], 32);
        double u1 = dq[1] + __shfl_xor(dq[1], 32);
        double u2 = dq[2] + __shfl_xor(dq[2], 32);
        double u3 = dq[3] + __shfl_xor(dq[3], 32);
        double w0 = (lane & 32) ? u2 : u0;
        double w1 = (lane & 32) ? u3 : u1;
        w0 += __shfl_xor(w0, 16);
        w1 += __shfl_xor(w1, 16);
        double y = (lane & 16) ? w1 : w0;
        y += __shfl_xor(y, 8); y += __shfl_xor(y, 4);
        y += __shfl_xor(y, 2); y += __shfl_xor(y, 1);
        if ((lane & 15) == 0) {
            const int g = lane >> 4;
            const double den = (y > 1e-6) ? y : 1e-6;
            invd[(size_t)b * S_ + c * DCH + t0 + g] = (float)(1.0 / den);
        }
    }
}

// ---------------------------------------------------------------------------
// chunk_prep (unchanged): q -> q*F, ik -> ik/F, F_T into f-slot of chunk row 0
// ---------------------------------------------------------------------------
__global__ __launch_bounds__(512)
void chunk_prep(float* __restrict__ qkv, float* __restrict__ gg)
{
    const int b = blockIdx.x >> 5;
    const int c = blockIdx.x & 31;
    const int d = threadIdx.x;
    float* qr = qkv + ((size_t)(b * S_ + c * CT)) * 1536 + d;
    float* gr = gg  + ((size_t)(b * S_ + c * CT)) * 1536 + d;
    float* ft = gr + 512;
    float F = 1.f;
    for (int u = 0; u < CT; ++u) {
        const float q = qr[0], ik = gr[0], f = gr[512];
        F *= f;
        qr[0] = q * F;
        gr[0] = ik / F;
        qr += 1536; gr += 1536;
    }
    ft[0] = F;
}

// ---------------------------------------------------------------------------
// chunk_A (unchanged): H1 = tril(Qt Kt^T) V -> hsb
// ---------------------------------------------------------------------------
__global__ __launch_bounds__(256)
void chunk_A(const float* __restrict__ qkv, const float* __restrict__ gg,
             float* __restrict__ h1out)
{
    const int b   = blockIdx.x >> 5;
    const int c   = blockIdx.x & 31;
    const int tid = threadIdx.x;
    const int t   = tid & 31;
    const int g   = tid >> 5;

    __shared__ float sA[32][33];

    const size_t rb = (size_t)(b * S_ + c * CT);
    const float* qr = qkv + (rb + t) * 1536;
    const float* kb = gg + rb * 1536;

    {
        const int s0 = g * 4;
        const float* k0 = kb + (size_t)(s0 + 0) * 1536;
        const float* k1 = kb + (size_t)(s0 + 1) * 1536;
        const float* k2 = kb + (size_t)(s0 + 2) * 1536;
        const float* k3 = kb + (size_t)(s0 + 3) * 1536;
        float a0 = 0.f, a1 = 0.f, a2 = 0.f, a3 = 0.f;
        for (int d4 = 0; d4 < 512; d4 += 4) {
            float4 qv = *(const float4*)(qr + d4);
            float4 x0 = *(const float4*)(k0 + d4);
            float4 x1 = *(const float4*)(k1 + d4);
            float4 x2 = *(const float4*)(k2 + d4);
            float4 x3 = *(const float4*)(k3 + d4);
            a0 = fmaf(qv.x, x0.x, a0); a0 = fmaf(qv.y, x0.y, a0);
            a0 = fmaf(qv.z, x0.z, a0); a0 = fmaf(qv.w, x0.w, a0);
            a1 = fmaf(qv.x, x1.x, a1); a1 = fmaf(qv.y, x1.y, a1);
            a1 = fmaf(qv.z, x1.z, a1); a1 = fmaf(qv.w, x1.w, a1);
            a2 = fmaf(qv.x, x2.x, a2); a2 = fmaf(qv.y, x2.y, a2);
            a2 = fmaf(qv.z, x2.z, a2); a2 = fmaf(qv.w, x2.w, a2);
            a3 = fmaf(qv.x, x3.x, a3); a3 = fmaf(qv.y, x3.y, a3);
            a3 = fmaf(qv.z, x3.z, a3); a3 = fmaf(qv.w, x3.w, a3);
        }
        sA[t][s0 + 0] = (s0 + 0 <= t) ? a0 : 0.f;
        sA[t][s0 + 1] = (s0 + 1 <= t) ? a1 : 0.f;
        sA[t][s0 + 2] = (s0 + 2 <= t) ? a2 : 0.f;
        sA[t][s0 + 3] = (s0 + 3 <= t) ? a3 : 0.f;
    }
    __syncthreads();

    {
        const int e0 = g * 64;
        float4 h[16];
#pragma unroll
        for (int m = 0; m < 16; ++m) h[m] = make_float4(0.f, 0.f, 0.f, 0.f);
        const float* vb = qkv + rb * 1536 + 1024 + e0;
        for (int s = 0; s < CT; ++s) {
            const float a = sA[t][s];
            const float* vr = vb + (size_t)s * 1536;
#pragma unroll
            for (int m = 0; m < 16; ++m) {
                float4 vv = *(const float4*)(vr + m * 4);
                h[m].x = fmaf(a, vv.x, h[m].x);
                h[m].y = fmaf(a, vv.y, h[m].y);
                h[m].z = fmaf(a, vv.z, h[m].z);
                h[m].w = fmaf(a, vv.w, h[m].w);
            }
        }
        float* orow = h1out + (rb + t) * 512 + e0;
#pragma unroll
        for (int m = 0; m < 16; ++m) *(float4*)(orow + m * 4) = h[m];
    }
}

// ---------------------------------------------------------------------------
// chunk_state: sequential chunk recurrence, NO dots / NO reduces.
// grid 256 = 8b x 32 e-blocks, 4 waves/block, wave owns 4 e-cols x 512 d.
// Per chunk: snapshot C0 as bf16 [slot][b][e][d] (coalesced: e is
// wave-uniform), Cacc += kt (x) v over 32 steps, C = F_T o (C + Cacc).
// Phased: processes chunks [c0, c0+nc); carries C via Cst between phases.
// ---------------------------------------------------------------------------
__global__ __launch_bounds__(256)
void chunk_state(const float* __restrict__ qkv, const float* __restrict__ gg,
                 unsigned short* __restrict__ snap, float* __restrict__ Cst,
                 float* __restrict__ CfO, int c0, int nc)
{
    const int tid  = threadIdx.x;
    const int lane = tid & 63;
    const int wv   = tid >> 6;
    const int b    = blockIdx.x & 7;
    const int ew   = (blockIdx.x >> 3) * 16 + wv * 4;
    const int d0   = 4 * lane;

    const float* qb = qkv + (size_t)b * S_ * 1536;
    const float* gb = gg  + (size_t)b * S_ * 1536;

    float4 C[2][4];
    if (c0 == 0) {
#pragma unroll
        for (int r = 0; r < 2; ++r)
#pragma unroll
            for (int j = 0; j < 4; ++j) C[r][j] = make_float4(0.f, 0.f, 0.f, 0.f);
    } else {
#pragma unroll
        for (int r = 0; r < 2; ++r)
#pragma unroll
            for (int j = 0; j < 4; ++j)
                C[r][j] = *(const float4*)&Cst[((size_t)b * 512 + 256 * r + d0 + j) * 512 + ew];
    }

    for (int lc = 0; lc < nc; ++lc) {
        const int c  = c0 + lc;
        const int t0 = c * CT;

        if (c > 0) {   // snapshot C0 (pre-update) as bf16, [e][d]-major
            const size_t sb = ((size_t)lc * 8 + b) * 512;
#pragma unroll
            for (int je = 0; je < 4; ++je) {
                ushort4 s0, s1;
                s0.x = f2bf(((const float*)&C[0][0])[je]);
                s0.y = f2bf(((const float*)&C[0][1])[je]);
                s0.z = f2bf(((const float*)&C[0][2])[je]);
                s0.w = f2bf(((const float*)&C[0][3])[je]);
                s1.x = f2bf(((const float*)&C[1][0])[je]);
                s1.y = f2bf(((const float*)&C[1][1])[je]);
                s1.z = f2bf(((const float*)&C[1][2])[je]);
                s1.w = f2bf(((const float*)&C[1][3])[je]);
                unsigned short* rowp = snap + (sb + ew + je) * 512;
                *(ushort4*)(rowp + d0)       = s0;
                *(ushort4*)(rowp + 256 + d0) = s1;
            }
        }

        float4 Cacc[2][4];
#pragma unroll
        for (int r = 0; r < 2; ++r)
#pragma unroll
            for (int j = 0; j < 4; ++j) Cacc[r][j] = make_float4(0.f, 0.f, 0.f, 0.f);

#pragma unroll 4
        for (int u = 0; u < CT; ++u) {
            const float* gr = gb + (size_t)(t0 + u) * 1536;
            float4 k0 = *(const float4*)(gr + d0);
            float4 k1 = *(const float4*)(gr + 256 + d0);
            float4 v4 = *(const float4*)(qb + (size_t)(t0 + u) * 1536 + 1024 + ew);
            const float* k0p = (const float*)&k0;
            const float* k1p = (const float*)&k1;
#pragma unroll
            for (int j = 0; j < 4; ++j) {
                const float ka = k0p[j], kc = k1p[j];
                Cacc[0][j].x = fmaf(ka, v4.x, Cacc[0][j].x);
                Cacc[0][j].y = fmaf(ka, v4.y, Cacc[0][j].y);
                Cacc[0][j].z = fmaf(ka, v4.z, Cacc[0][j].z);
                Cacc[0][j].w = fmaf(ka, v4.w, Cacc[0][j].w);
                Cacc[1][j].x = fmaf(kc, v4.x, Cacc[1][j].x);
                Cacc[1][j].y = fmaf(kc, v4.y, Cacc[1][j].y);
                Cacc[1][j].z = fmaf(kc, v4.z, Cacc[1][j].z);
                Cacc[1][j].w = fmaf(kc, v4.w, Cacc[1][j].w);
            }
        }

        const float* ftp = gb + (size_t)t0 * 1536 + 512;
        float4 F0 = *(const float4*)(ftp + d0);
        float4 F1 = *(const float4*)(ftp + 256 + d0);
        const float* f0p = (const float*)&F0;
        const float* f1p = (const float*)&F1;
#pragma unroll
        for (int j = 0; j < 4; ++j) {
            C[0][j].x = f0p[j] * (C[0][j].x + Cacc[0][j].x);
            C[0][j].y = f0p[j] * (C[0][j].y + Cacc[0][j].y);
            C[0][j].z = f0p[j] * (C[0][j].z + Cacc[0][j].z);
            C[0][j].w = f0p[j] * (C[0][j].w + Cacc[0][j].w);
            C[1][j].x = f1p[j] * (C[1][j].x + Cacc[1][j].x);
            C[1][j].y = f1p[j] * (C[1][j].y + Cacc[1][j].y);
            C[1][j].z = f1p[j] * (C[1][j].z + Cacc[1][j].z);
            C[1][j].w = f1p[j] * (C[1][j].w + Cacc[1][j].w);
        }
    }

    float* outp = (c0 + nc == NCT) ? CfO : Cst;
#pragma unroll
    for (int r = 0; r < 2; ++r)
#pragma unroll
        for (int j = 0; j < 4; ++j)
            *(float4*)&outp[((size_t)b * 512 + 256 * r + d0 + j) * 512 + ew] = C[r][j];
}

// ---------------------------------------------------------------------------
// chunk_h2: H2 = Qt @ C0 per chunk (bf16 C0 rows, Qt in LDS), fused combine
// h = (H1 + H2) * o * invd  -> hs (in place over H1).
// grid (eh, lc, b) = (2, nc, 8); 256 thr; thread (t,g) owns 32 e-cols.
// ---------------------------------------------------------------------------
__global__ __launch_bounds__(256)
void chunk_h2(const float* __restrict__ qkv, const float* __restrict__ gg,
              const unsigned short* __restrict__ snap,
              const float* __restrict__ invd,
              float* __restrict__ hs, float* __restrict__ hlO, int c0)
{
    const int eh  = blockIdx.x;
    const int lc  = blockIdx.y;
    const int b   = blockIdx.z;
    const int c   = c0 + lc;
    const int tid = threadIdx.x;
    const int t   = tid & 31;
    const int g   = tid >> 5;
    const int e0  = eh * 256 + g * 32;

    __shared__ float sQ[32][516];

    const size_t rb = (size_t)(b * S_ + c * CT);
    for (int i = tid; i < 32 * 128; i += 256) {
        const int row = i >> 7, c4 = (i & 127) * 4;
        *(float4*)&sQ[row][c4] = *(const float4*)(qkv + (rb + row) * 1536 + c4);
    }
    __syncthreads();

    float4 h[8];
#pragma unroll
    for (int m = 0; m < 8; ++m) h[m] = make_float4(0.f, 0.f, 0.f, 0.f);

    if (c > 0) {
        const unsigned short* cb = snap + (((size_t)lc * 8 + b) * 512 + e0) * 512;
#pragma unroll
        for (int e4 = 0; e4 < 8; ++e4) {
            const unsigned short* r0 = cb + (size_t)(e4 * 4 + 0) * 512;
            const unsigned short* r1 = cb + (size_t)(e4 * 4 + 1) * 512;
            const unsigned short* r2 = cb + (size_t)(e4 * 4 + 2) * 512;
            const unsigned short* r3 = cb + (size_t)(e4 * 4 + 3) * 512;
            float a0 = 0.f, a1 = 0.f, a2 = 0.f, a3 = 0.f;
            for (int d = 0; d < 512; d += 4) {
                float4 qv = *(const float4*)&sQ[t][d];
                ushort4 x0 = *(const ushort4*)(r0 + d);
                ushort4 x1 = *(const ushort4*)(r1 + d);
                ushort4 x2 = *(const ushort4*)(r2 + d);
                ushort4 x3 = *(const ushort4*)(r3 + d);
                a0 = fmaf(qv.x, bf2f(x0.x), a0); a0 = fmaf(qv.y, bf2f(x0.y), a0);
                a0 = fmaf(qv.z, bf2f(x0.z), a0); a0 = fmaf(qv.w, bf2f(x0.w), a0);
                a1 = fmaf(qv.x, bf2f(x1.x), a1); a1 = fmaf(qv.y, bf2f(x1.y), a1);
                a1 = fmaf(qv.z, bf2f(x1.z), a1); a1 = fmaf(qv.w, bf2f(x1.w), a1);
                a2 = fmaf(qv.x, bf2f(x2.x), a2); a2 = fmaf(qv.y, bf2f(x2.y), a2);
                a2 = fmaf(qv.z, bf2f(x2.z), a2); a2 = fmaf(qv.w, bf2f(x2.w), a2);
                a3 = fmaf(qv.x, bf2f(x3.x), a3); a3 = fmaf(qv.y, bf2f(x3.y), a3);
                a3 = fmaf(qv.z, bf2f(x3.z), a3); a3 = fmaf(qv.w, bf2f(x3.w), a3);
            }
            h[e4] = make_float4(a0, a1, a2, a3);
        }
    }

    // combine: h_final = (H1 + H2) * o * invd
    const float ivt = invd[(size_t)b * S_ + c * CT + t];
    float* hrow = hs + (rb + t) * 512 + e0;
    const float* orow = gg + (rb + t) * 1536 + 1024 + e0;
    const bool last = (c * CT + t == S_ - 1);
#pragma unroll
    for (int m = 0; m < 8; ++m) {
        float4 h1 = *(const float4*)(hrow + m * 4);
        float4 ov = *(const float4*)(orow + m * 4);
        float4 r;
        r.x = (h[m].x + h1.x) * ov.x * ivt;
        r.y = (h[m].y + h1.y) * ov.y * ivt;
        r.z = (h[m].z + h1.z) * ov.z * ivt;
        r.w = (h[m].w + h1.w) * ov.w * ivt;
        *(float4*)(hrow + m * 4) = r;
        if (last) *(float4*)(hlO + (size_t)b * 512 + e0 + m * 4) = r;
    }
}

// ---------------------------------------------------------------------------
extern "C" void kernel_launch(void* const* d_in, const int* in_sizes, int n_in,
                              void* d_out, int out_size, void* d_ws, size_t ws_size,
                              hipStream_t stream)
{
    const float* x    = (const float*)d_in[0];
    const float* W_in = (const float*)d_in[1];
    const float* b_in = (const float*)d_in[2];
    const float* W_ig = (const float*)d_in[3];
    const float* b_ig = (const float*)d_in[4];
    const float* W_fg = (const float*)d_in[5];
    const float* b_fg = (const float*)d_in[6];
    const float* W_og = (const float*)d_in[7];
    const float* b_og = (const float*)d_in[8];
    const float* W_out= (const float*)d_in[9];
    const float* b_out= (const float*)d_in[10];

    float* out   = (float*)d_out;                       // [8,1024,512]
    float* CfO   = out + (size_t)8 * 1024 * 512;        // [8,512,512]
    float* nfO   = CfO + (size_t)8 * 512 * 512;         // [8,512]
    float* hlO   = nfO + (size_t)8 * 512;               // [8,512]

    float* qkv = (float*)d_ws;                          // [8192,1536]
    float* gg  = qkv + (size_t)8192 * 1536;             // [8192,1536]
    float* hsb = gg  + (size_t)8192 * 1536;             // [8192,512]
    double* nend = (double*)hsb;                        // overlay (dead later)
    double* Dend = nend + (size_t)8 * NDCH * 512;
    double* n0a  = Dend + (size_t)8 * NDCH * 512;
    float*  invd = hsb + (size_t)8192 * 512;            // [8,1024]
    float*  Cst  = invd + 8192;                         // [8,512,512] f32
    unsigned short* snap = (unsigned short*)(Cst + (size_t)8 * 512 * 512);

    // phase sizing by available workspace
    const size_t BASE   = ((size_t)(8192 * 1536) * 2 + 8192 * 512 + 8192) * 4
                        + (size_t)8 * 512 * 512 * 4;     // through Cst
    const size_t SNAPC  = (size_t)8 * 512 * 512 * 2;     // per-chunk snapshot
    int nc = 2;
    if (ws_size >= BASE + 32 * SNAPC)      nc = 32;
    else if (ws_size >= BASE + 8 * SNAPC)  nc = 8;

    gemm_act<0><<<dim3(12, 64), 256, 0, stream>>>(
        x, 512, W_in, W_in, W_in, b_in, b_in, b_in, qkv, 1536);
    gemm_act<1><<<dim3(12, 64), 256, 0, stream>>>(
        qkv + 1024, 1536, W_ig, W_fg, W_og, b_ig, b_fg, b_og, gg, 1536);
    nscan_local <<<512, 512, 0, stream>>>(gg, nend, Dend);
    nscan_stitch<<<  8, 512, 0, stream>>>(nend, Dend, n0a, nfO);
    denom_kernel<<<128, 256, 0, stream>>>(qkv, gg, n0a, invd);
    chunk_prep<<<256, 512, 0, stream>>>(qkv, gg);
    chunk_A<<<256, 256, 0, stream>>>(qkv, gg, hsb);
    for (int c0 = 0; c0 < NCT; c0 += nc) {
        chunk_state<<<256, 256, 0, stream>>>(qkv, gg, snap, Cst, CfO, c0, nc);
        chunk_h2<<<dim3(2, nc, 8), 256, 0, stream>>>(qkv, gg, snap, invd, hsb, hlO, c0);
    }
    gemm_act<2><<<dim3(4, 64), 256, 0, stream>>>(
        hsb, 512, W_out, W_out, W_out, b_out, b_out, b_out, out, 512);
}

// Round 8
// 696.604 us; speedup vs baseline: 1.9369x; 1.1682x over previous
//
#include <hip/hip_runtime.h>

#define S_ 1024
#define D_ 512
#define DCH 16      // denom chunk length (f64 pipeline)
#define NDCH 64     // denom chunks per batch
#define CT 32       // GEMM-scan chunk length
#define NCT 32      // GEMM-scan chunks per batch

using bf16x8 = __attribute__((ext_vector_type(8))) short;
using f32x4  = __attribute__((ext_vector_type(4))) float;

__device__ __forceinline__ unsigned short f2bf(float x) {
    unsigned int u = __float_as_uint(x);
    u = (u + 0x7FFFu + ((u >> 16) & 1u)) >> 16;
    return (unsigned short)u;
}
__device__ __forceinline__ float bf2f(unsigned short s) {
    return __uint_as_float(((unsigned int)s) << 16);
}
__device__ __forceinline__ bf16x8 cvt8(const float* __restrict__ p) {
    float4 a = *(const float4*)p;
    float4 b = *(const float4*)(p + 4);
    bf16x8 r;
    r[0] = (short)f2bf(a.x); r[1] = (short)f2bf(a.y);
    r[2] = (short)f2bf(a.z); r[3] = (short)f2bf(a.w);
    r[4] = (short)f2bf(b.x); r[5] = (short)f2bf(b.y);
    r[6] = (short)f2bf(b.z); r[7] = (short)f2bf(b.w);
    return r;
}

// ---------------------------------------------------------------------------
// GEMM + bias + activation (unchanged)
// ---------------------------------------------------------------------------
template<int MODE>
__global__ __launch_bounds__(256)
void gemm_act(const float* __restrict__ A, int lda,
              const float* __restrict__ W0, const float* __restrict__ W1,
              const float* __restrict__ W2,
              const float* __restrict__ bb0, const float* __restrict__ bb1,
              const float* __restrict__ bb2,
              float* __restrict__ Co, int ldc)
{
    const int tid = threadIdx.x;
    const int n0  = blockIdx.x * 128;
    const int m0  = blockIdx.y * 128;

    const float* Bp; const float* bias; int ldb;
    if (MODE == 1) {
        const int g  = n0 >> 9;
        const int nn = n0 & 511;
        Bp   = (g == 0 ? W0 : g == 1 ? W1 : W2) + nn;
        bias = (g == 0 ? bb0 : g == 1 ? bb1 : bb2) + nn;
        ldb  = 512;
    } else {
        Bp   = W0 + n0;
        bias = bb0 + n0;
        ldb  = (MODE == 0 ? 2048 : 512);
    }

    __shared__ float As[16][128];
    __shared__ float Bs[16][128];

    float acc[8][8];
#pragma unroll
    for (int i = 0; i < 8; ++i)
#pragma unroll
        for (int j = 0; j < 8; ++j) acc[i][j] = 0.f;

    const int ar = tid >> 2;
    const int ac = (tid & 3) * 4;
    const int br = tid >> 5;
    const int bc = (tid & 31) * 4;
    const int ty = tid >> 4;
    const int tx = tid & 15;

    const float* Ap = A + (size_t)(m0 + ar) * lda + ac;
    const float* Bq = Bp + (size_t)br * ldb + bc;

    for (int k0 = 0; k0 < 512; k0 += 16) {
        float4 a0 = *(const float4*)(Ap);
        float4 a1 = *(const float4*)(Ap + (size_t)64 * lda);
        float4 b0 = *(const float4*)(Bq);
        float4 b1 = *(const float4*)(Bq + (size_t)8 * ldb);
        Ap += 16; Bq += (size_t)16 * ldb;

        __syncthreads();
        As[ac + 0][ar]      = a0.x; As[ac + 1][ar]      = a0.y;
        As[ac + 2][ar]      = a0.z; As[ac + 3][ar]      = a0.w;
        As[ac + 0][ar + 64] = a1.x; As[ac + 1][ar + 64] = a1.y;
        As[ac + 2][ar + 64] = a1.z; As[ac + 3][ar + 64] = a1.w;
        *(float4*)&Bs[br][bc]     = b0;
        *(float4*)&Bs[br + 8][bc] = b1;
        __syncthreads();

#pragma unroll
        for (int kk = 0; kk < 16; ++kk) {
            float4 aL = *(const float4*)&As[kk][ty * 4];
            float4 aH = *(const float4*)&As[kk][64 + ty * 4];
            float4 bL = *(const float4*)&Bs[kk][tx * 4];
            float4 bH = *(const float4*)&Bs[kk][64 + tx * 4];
            float av[8] = {aL.x, aL.y, aL.z, aL.w, aH.x, aH.y, aH.z, aH.w};
            float bv[8] = {bL.x, bL.y, bL.z, bL.w, bH.x, bH.y, bH.z, bH.w};
#pragma unroll
            for (int i = 0; i < 8; ++i)
#pragma unroll
                for (int j = 0; j < 8; ++j)
                    acc[i][j] = fmaf(av[i], bv[j], acc[i][j]);
        }
    }

    float bv[8];
#pragma unroll
    for (int j = 0; j < 8; ++j) {
        const int c = (j < 4) ? (tx * 4 + j) : (64 + tx * 4 + j - 4);
        bv[j] = bias[c];
    }
#pragma unroll
    for (int i = 0; i < 8; ++i) {
        const int m = m0 + ((i < 4) ? (ty * 4 + i) : (64 + ty * 4 + i - 4));
        float vals[8];
#pragma unroll
        for (int j = 0; j < 8; ++j) {
            float v = acc[i][j] + bv[j];
            if (MODE == 0) {
                const int cg = n0 + ((j < 4) ? (tx * 4 + j) : (64 + tx * 4 + j - 4));
                if (cg < 1024) v = tanhf(v);
            } else if (MODE == 1) {
                v = 1.0f / (1.0f + expf(-v));
            }
            vals[j] = v;
        }
        if (MODE == 1 && n0 < 512) {
            const float* krow = A + (size_t)m * lda - 512;
            float4 kl = *(const float4*)(krow + n0 + tx * 4);
            float4 kh = *(const float4*)(krow + n0 + 64 + tx * 4);
            vals[0] *= kl.x; vals[1] *= kl.y; vals[2] *= kl.z; vals[3] *= kl.w;
            vals[4] *= kh.x; vals[5] *= kh.y; vals[6] *= kh.z; vals[7] *= kh.w;
        }
        float* row = Co + (size_t)m * ldc + n0;
        *(float4*)&row[tx * 4]      = make_float4(vals[0], vals[1], vals[2], vals[3]);
        *(float4*)&row[64 + tx * 4] = make_float4(vals[4], vals[5], vals[6], vals[7]);
    }
}

// ---------------------------------------------------------------------------
// f64 denominator pipeline (unchanged)
// ---------------------------------------------------------------------------
__global__ __launch_bounds__(512)
void nscan_local(const float* __restrict__ GG,
                 double* __restrict__ nend, double* __restrict__ Dend)
{
    const int b = blockIdx.x >> 6;
    const int c = blockIdx.x & 63;
    const int d = threadIdx.x;
    const float* gb = GG + (size_t)b * S_ * 1536 + (size_t)c * DCH * 1536;
    double n = 0.0, P = 1.0;
    for (int u = 0; u < DCH; ++u) {
        const float* row = gb + (size_t)u * 1536;
        const double ik = (double)row[d];
        const double f  = (double)row[512 + d];
        n = fma(f, n, ik);
        P *= f;
    }
    nend[(size_t)blockIdx.x * 512 + d] = n;
    Dend[(size_t)blockIdx.x * 512 + d] = P;
}

__global__ __launch_bounds__(512)
void nscan_stitch(const double* __restrict__ nend, const double* __restrict__ Dend,
                  double* __restrict__ n0a, float* __restrict__ nfO)
{
    const int b = blockIdx.x;
    const int d = threadIdx.x;
    double n0 = 0.0;
    for (int c = 0; c < NDCH; ++c) {
        const size_t idx = ((size_t)(b * NDCH + c)) * 512 + d;
        n0a[idx] = n0;
        n0 = fma(Dend[idx], n0, nend[idx]);
    }
    nfO[(size_t)b * 512 + d] = (float)n0;
}

__global__ __launch_bounds__(256)
void denom_kernel(const float* __restrict__ QKV, const float* __restrict__ GG,
                  const double* __restrict__ n0a, float* __restrict__ invd)
{
    const int lane = threadIdx.x & 63;
    const int widx = blockIdx.x * 4 + (threadIdx.x >> 6);
    const int b    = widx >> 6;
    const int c    = widx & 63;
    const int d0   = 4 * lane;

    const float* qb = QKV + (size_t)b * S_ * 1536 + (size_t)c * DCH * 1536;
    const float* gb = GG  + (size_t)b * S_ * 1536 + (size_t)c * DCH * 1536;
    const double* sp = n0a + (size_t)widx * 512;

    double n[2][4];
#pragma unroll
    for (int r = 0; r < 2; ++r) {
        double2 a = *(const double2*)(sp + d0 + 256 * r);
        double2 bb = *(const double2*)(sp + d0 + 256 * r + 2);
        n[r][0] = a.x; n[r][1] = a.y; n[r][2] = bb.x; n[r][3] = bb.y;
    }

    for (int t0 = 0; t0 < DCH; t0 += 4) {
        double dq[4];
#pragma unroll
        for (int i = 0; i < 4; ++i) {
            const float* qr = qb + (size_t)(t0 + i) * 1536;
            const float* gr = gb + (size_t)(t0 + i) * 1536;
            double acc = 0.0;
#pragma unroll
            for (int r = 0; r < 2; ++r) {
                float4 qf = *(const float4*)(qr + d0 + 256 * r);
                float4 kf = *(const float4*)(gr + d0 + 256 * r);
                float4 ff = *(const float4*)(gr + 512 + d0 + 256 * r);
                const float* qp = (const float*)&qf;
                const float* kp = (const float*)&kf;
                const float* fp = (const float*)&ff;
#pragma unroll
                for (int j = 0; j < 4; ++j) {
                    n[r][j] = fma((double)fp[j], n[r][j], (double)kp[j]);
                    acc = fma((double)qp[j], n[r][j], acc);
                }
            }
            dq[i] = acc;
        }
        double u0 = dq[0] + __shfl_xor(dq[0], 32);
        double u1 = dq[1] + __shfl_xor(dq[1], 32);
        double u2 = dq[2] + __shfl_xor(dq[2], 32);
        double u3 = dq[3] + __shfl_xor(dq[3], 32);
        double w0 = (lane & 32) ? u2 : u0;
        double w1 = (lane & 32) ? u3 : u1;
        w0 += __shfl_xor(w0, 16);
        w1 += __shfl_xor(w1, 16);
        double y = (lane & 16) ? w1 : w0;
        y += __shfl_xor(y, 8); y += __shfl_xor(y, 4);
        y += __shfl_xor(y, 2); y += __shfl_xor(y, 1);
        if ((lane & 15) == 0) {
            const int g = lane >> 4;
            const double den = (y > 1e-6) ? y : 1e-6;
            invd[(size_t)b * S_ + c * DCH + t0 + g] = (float)(1.0 / den);
        }
    }
}

// ---------------------------------------------------------------------------
// chunk_prep (unchanged): q -> q*F, ik -> ik/F, F_T into f-slot of chunk row 0
// ---------------------------------------------------------------------------
__global__ __launch_bounds__(512)
void chunk_prep(float* __restrict__ qkv, float* __restrict__ gg)
{
    const int b = blockIdx.x >> 5;
    const int c = blockIdx.x & 31;
    const int d = threadIdx.x;
    float* qr = qkv + ((size_t)(b * S_ + c * CT)) * 1536 + d;
    float* gr = gg  + ((size_t)(b * S_ + c * CT)) * 1536 + d;
    float* ft = gr + 512;
    float F = 1.f;
    for (int u = 0; u < CT; ++u) {
        const float q = qr[0], ik = gr[0], f = gr[512];
        F *= f;
        qr[0] = q * F;
        gr[0] = ik / F;
        qr += 1536; gr += 1536;
    }
    ft[0] = F;
}

// ---------------------------------------------------------------------------
// chunk_A (unchanged): H1 = tril(Qt Kt^T) V -> hsb
// ---------------------------------------------------------------------------
__global__ __launch_bounds__(256)
void chunk_A(const float* __restrict__ qkv, const float* __restrict__ gg,
             float* __restrict__ h1out)
{
    const int b   = blockIdx.x >> 5;
    const int c   = blockIdx.x & 31;
    const int tid = threadIdx.x;
    const int t   = tid & 31;
    const int g   = tid >> 5;

    __shared__ float sA[32][33];

    const size_t rb = (size_t)(b * S_ + c * CT);
    const float* qr = qkv + (rb + t) * 1536;
    const float* kb = gg + rb * 1536;

    {
        const int s0 = g * 4;
        const float* k0 = kb + (size_t)(s0 + 0) * 1536;
        const float* k1 = kb + (size_t)(s0 + 1) * 1536;
        const float* k2 = kb + (size_t)(s0 + 2) * 1536;
        const float* k3 = kb + (size_t)(s0 + 3) * 1536;
        float a0 = 0.f, a1 = 0.f, a2 = 0.f, a3 = 0.f;
        for (int d4 = 0; d4 < 512; d4 += 4) {
            float4 qv = *(const float4*)(qr + d4);
            float4 x0 = *(const float4*)(k0 + d4);
            float4 x1 = *(const float4*)(k1 + d4);
            float4 x2 = *(const float4*)(k2 + d4);
            float4 x3 = *(const float4*)(k3 + d4);
            a0 = fmaf(qv.x, x0.x, a0); a0 = fmaf(qv.y, x0.y, a0);
            a0 = fmaf(qv.z, x0.z, a0); a0 = fmaf(qv.w, x0.w, a0);
            a1 = fmaf(qv.x, x1.x, a1); a1 = fmaf(qv.y, x1.y, a1);
            a1 = fmaf(qv.z, x1.z, a1); a1 = fmaf(qv.w, x1.w, a1);
            a2 = fmaf(qv.x, x2.x, a2); a2 = fmaf(qv.y, x2.y, a2);
            a2 = fmaf(qv.z, x2.z, a2); a2 = fmaf(qv.w, x2.w, a2);
            a3 = fmaf(qv.x, x3.x, a3); a3 = fmaf(qv.y, x3.y, a3);
            a3 = fmaf(qv.z, x3.z, a3); a3 = fmaf(qv.w, x3.w, a3);
        }
        sA[t][s0 + 0] = (s0 + 0 <= t) ? a0 : 0.f;
        sA[t][s0 + 1] = (s0 + 1 <= t) ? a1 : 0.f;
        sA[t][s0 + 2] = (s0 + 2 <= t) ? a2 : 0.f;
        sA[t][s0 + 3] = (s0 + 3 <= t) ? a3 : 0.f;
    }
    __syncthreads();

    {
        const int e0 = g * 64;
        float4 h[16];
#pragma unroll
        for (int m = 0; m < 16; ++m) h[m] = make_float4(0.f, 0.f, 0.f, 0.f);
        const float* vb = qkv + rb * 1536 + 1024 + e0;
        for (int s = 0; s < CT; ++s) {
            const float a = sA[t][s];
            const float* vr = vb + (size_t)s * 1536;
#pragma unroll
            for (int m = 0; m < 16; ++m) {
                float4 vv = *(const float4*)(vr + m * 4);
                h[m].x = fmaf(a, vv.x, h[m].x);
                h[m].y = fmaf(a, vv.y, h[m].y);
                h[m].z = fmaf(a, vv.z, h[m].z);
                h[m].w = fmaf(a, vv.w, h[m].w);
            }
        }
        float* orow = h1out + (rb + t) * 512 + e0;
#pragma unroll
        for (int m = 0; m < 16; ++m) *(float4*)(orow + m * 4) = h[m];
    }
}

// ---------------------------------------------------------------------------
// chunk_state (unchanged): sequential chunk recurrence + bf16 C0 snapshots
// ---------------------------------------------------------------------------
__global__ __launch_bounds__(256)
void chunk_state(const float* __restrict__ qkv, const float* __restrict__ gg,
                 unsigned short* __restrict__ snap, float* __restrict__ Cst,
                 float* __restrict__ CfO, int c0, int nc)
{
    const int tid  = threadIdx.x;
    const int lane = tid & 63;
    const int wv   = tid >> 6;
    const int b    = blockIdx.x & 7;
    const int ew   = (blockIdx.x >> 3) * 16 + wv * 4;
    const int d0   = 4 * lane;

    const float* qb = qkv + (size_t)b * S_ * 1536;
    const float* gb = gg  + (size_t)b * S_ * 1536;

    float4 C[2][4];
    if (c0 == 0) {
#pragma unroll
        for (int r = 0; r < 2; ++r)
#pragma unroll
            for (int j = 0; j < 4; ++j) C[r][j] = make_float4(0.f, 0.f, 0.f, 0.f);
    } else {
#pragma unroll
        for (int r = 0; r < 2; ++r)
#pragma unroll
            for (int j = 0; j < 4; ++j)
                C[r][j] = *(const float4*)&Cst[((size_t)b * 512 + 256 * r + d0 + j) * 512 + ew];
    }

    for (int lc = 0; lc < nc; ++lc) {
        const int c  = c0 + lc;
        const int t0 = c * CT;

        if (c > 0) {
            const size_t sb = ((size_t)lc * 8 + b) * 512;
#pragma unroll
            for (int je = 0; je < 4; ++je) {
                ushort4 s0, s1;
                s0.x = f2bf(((const float*)&C[0][0])[je]);
                s0.y = f2bf(((const float*)&C[0][1])[je]);
                s0.z = f2bf(((const float*)&C[0][2])[je]);
                s0.w = f2bf(((const float*)&C[0][3])[je]);
                s1.x = f2bf(((const float*)&C[1][0])[je]);
                s1.y = f2bf(((const float*)&C[1][1])[je]);
                s1.z = f2bf(((const float*)&C[1][2])[je]);
                s1.w = f2bf(((const float*)&C[1][3])[je]);
                unsigned short* rowp = snap + (sb + ew + je) * 512;
                *(ushort4*)(rowp + d0)       = s0;
                *(ushort4*)(rowp + 256 + d0) = s1;
            }
        }

        float4 Cacc[2][4];
#pragma unroll
        for (int r = 0; r < 2; ++r)
#pragma unroll
            for (int j = 0; j < 4; ++j) Cacc[r][j] = make_float4(0.f, 0.f, 0.f, 0.f);

#pragma unroll 4
        for (int u = 0; u < CT; ++u) {
            const float* gr = gb + (size_t)(t0 + u) * 1536;
            float4 k0 = *(const float4*)(gr + d0);
            float4 k1 = *(const float4*)(gr + 256 + d0);
            float4 v4 = *(const float4*)(qb + (size_t)(t0 + u) * 1536 + 1024 + ew);
            const float* k0p = (const float*)&k0;
            const float* k1p = (const float*)&k1;
#pragma unroll
            for (int j = 0; j < 4; ++j) {
                const float ka = k0p[j], kc = k1p[j];
                Cacc[0][j].x = fmaf(ka, v4.x, Cacc[0][j].x);
                Cacc[0][j].y = fmaf(ka, v4.y, Cacc[0][j].y);
                Cacc[0][j].z = fmaf(ka, v4.z, Cacc[0][j].z);
                Cacc[0][j].w = fmaf(ka, v4.w, Cacc[0][j].w);
                Cacc[1][j].x = fmaf(kc, v4.x, Cacc[1][j].x);
                Cacc[1][j].y = fmaf(kc, v4.y, Cacc[1][j].y);
                Cacc[1][j].z = fmaf(kc, v4.z, Cacc[1][j].z);
                Cacc[1][j].w = fmaf(kc, v4.w, Cacc[1][j].w);
            }
        }

        const float* ftp = gb + (size_t)t0 * 1536 + 512;
        float4 F0 = *(const float4*)(ftp + d0);
        float4 F1 = *(const float4*)(ftp + 256 + d0);
        const float* f0p = (const float*)&F0;
        const float* f1p = (const float*)&F1;
#pragma unroll
        for (int j = 0; j < 4; ++j) {
            C[0][j].x = f0p[j] * (C[0][j].x + Cacc[0][j].x);
            C[0][j].y = f0p[j] * (C[0][j].y + Cacc[0][j].y);
            C[0][j].z = f0p[j] * (C[0][j].z + Cacc[0][j].z);
            C[0][j].w = f0p[j] * (C[0][j].w + Cacc[0][j].w);
            C[1][j].x = f1p[j] * (C[1][j].x + Cacc[1][j].x);
            C[1][j].y = f1p[j] * (C[1][j].y + Cacc[1][j].y);
            C[1][j].z = f1p[j] * (C[1][j].z + Cacc[1][j].z);
            C[1][j].w = f1p[j] * (C[1][j].w + Cacc[1][j].w);
        }
    }

    float* outp = (c0 + nc == NCT) ? CfO : Cst;
#pragma unroll
    for (int r = 0; r < 2; ++r)
#pragma unroll
        for (int j = 0; j < 4; ++j)
            *(float4*)&outp[((size_t)b * 512 + 256 * r + d0 + j) * 512 + ew] = C[r][j];
}

// ---------------------------------------------------------------------------
// chunk_h2 (MFMA): H2 = Qt @ C0^T per chunk via mfma_f32_16x16x32_bf16.
// A = Qt rows (f32 -> RNE bf16 in-register), B = snap rows (bf16, [e][d] —
// already fragment-shaped: lane l&15 -> e, 8 contiguous d at 8*(l>>4)).
// grid (eh, lc, b) = (2, nc, 8), 256 thr; wave owns M=32 x N=64.
// Fused epilogue: h = (H1 + H2) * o * invd -> hs (in place over H1).
// ---------------------------------------------------------------------------
__global__ __launch_bounds__(256)
void chunk_h2(const float* __restrict__ qkv, const float* __restrict__ gg,
              const unsigned short* __restrict__ snap,
              const float* __restrict__ invd,
              float* __restrict__ hs, float* __restrict__ hlO, int c0)
{
    const int eh   = blockIdx.x;
    const int lc   = blockIdx.y;
    const int b    = blockIdx.z;
    const int c    = c0 + lc;
    const int tid  = threadIdx.x;
    const int lane = tid & 63;
    const int wv   = tid >> 6;
    const int n0   = eh * 256 + wv * 64;     // wave's e base
    const int l15  = lane & 15;
    const int kg   = lane >> 4;              // 0..3

    const size_t rb = (size_t)(b * S_ + c * CT);

    f32x4 acc[2][4];
#pragma unroll
    for (int mf = 0; mf < 2; ++mf)
#pragma unroll
        for (int nf = 0; nf < 4; ++nf) acc[mf][nf] = (f32x4){0.f, 0.f, 0.f, 0.f};

    if (c > 0) {
        const unsigned short* cb = snap + ((size_t)(lc * 8 + b) * 512) * 512;
        const float* q0p = qkv + (rb + l15) * 1536;
        const float* q1p = qkv + (rb + 16 + l15) * 1536;
#pragma unroll 4
        for (int k0 = 0; k0 < 512; k0 += 32) {
            const int kb = k0 + kg * 8;
            bf16x8 a0 = cvt8(q0p + kb);
            bf16x8 a1 = cvt8(q1p + kb);
#pragma unroll
            for (int nf = 0; nf < 4; ++nf) {
                const unsigned short* bp = cb + (size_t)(n0 + nf * 16 + l15) * 512 + kb;
                bf16x8 bf = *(const bf16x8*)bp;
                acc[0][nf] = __builtin_amdgcn_mfma_f32_16x16x32_bf16(a0, bf, acc[0][nf], 0, 0, 0);
                acc[1][nf] = __builtin_amdgcn_mfma_f32_16x16x32_bf16(a1, bf, acc[1][nf], 0, 0, 0);
            }
        }
    }

    // epilogue: D row = 4*kg + vi, col = l15
    const float* ivp = invd + (size_t)b * S_ + c * CT;
#pragma unroll
    for (int mf = 0; mf < 2; ++mf) {
#pragma unroll
        for (int vi = 0; vi < 4; ++vi) {
            const int tl  = mf * 16 + kg * 4 + vi;
            const float ivt = ivp[tl];
            float* hrow       = hs + (rb + tl) * 512;
            const float* orow = gg + (rb + tl) * 1536 + 1024;
            const bool last = (c * CT + tl == S_ - 1);
#pragma unroll
            for (int nf = 0; nf < 4; ++nf) {
                const int e  = n0 + nf * 16 + l15;
                const float h1 = hrow[e];
                const float ov = orow[e];
                const float r  = (acc[mf][nf][vi] + h1) * ov * ivt;
                hrow[e] = r;
                if (last) hlO[(size_t)b * 512 + e] = r;
            }
        }
    }
}

// ---------------------------------------------------------------------------
extern "C" void kernel_launch(void* const* d_in, const int* in_sizes, int n_in,
                              void* d_out, int out_size, void* d_ws, size_t ws_size,
                              hipStream_t stream)
{
    const float* x    = (const float*)d_in[0];
    const float* W_in = (const float*)d_in[1];
    const float* b_in = (const float*)d_in[2];
    const float* W_ig = (const float*)d_in[3];
    const float* b_ig = (const float*)d_in[4];
    const float* W_fg = (const float*)d_in[5];
    const float* b_fg = (const float*)d_in[6];
    const float* W_og = (const float*)d_in[7];
    const float* b_og = (const float*)d_in[8];
    const float* W_out= (const float*)d_in[9];
    const float* b_out= (const float*)d_in[10];

    float* out   = (float*)d_out;                       // [8,1024,512]
    float* CfO   = out + (size_t)8 * 1024 * 512;        // [8,512,512]
    float* nfO   = CfO + (size_t)8 * 512 * 512;         // [8,512]
    float* hlO   = nfO + (size_t)8 * 512;               // [8,512]

    float* qkv = (float*)d_ws;                          // [8192,1536]
    float* gg  = qkv + (size_t)8192 * 1536;             // [8192,1536]
    float* hsb = gg  + (size_t)8192 * 1536;             // [8192,512]
    double* nend = (double*)hsb;                        // overlay (dead later)
    double* Dend = nend + (size_t)8 * NDCH * 512;
    double* n0a  = Dend + (size_t)8 * NDCH * 512;
    float*  invd = hsb + (size_t)8192 * 512;            // [8,1024]
    float*  Cst  = invd + 8192;                         // [8,512,512] f32
    unsigned short* snap = (unsigned short*)(Cst + (size_t)8 * 512 * 512);

    const size_t BASE   = ((size_t)(8192 * 1536) * 2 + 8192 * 512 + 8192) * 4
                        + (size_t)8 * 512 * 512 * 4;
    const size_t SNAPC  = (size_t)8 * 512 * 512 * 2;
    int nc = 2;
    if (ws_size >= BASE + 32 * SNAPC)      nc = 32;
    else if (ws_size >= BASE + 8 * SNAPC)  nc = 8;

    gemm_act<0><<<dim3(12, 64), 256, 0, stream>>>(
        x, 512, W_in, W_in, W_in, b_in, b_in, b_in, qkv, 1536);
    gemm_act<1><<<dim3(12, 64), 256, 0, stream>>>(
        qkv + 1024, 1536, W_ig, W_fg, W_og, b_ig, b_fg, b_og, gg, 1536);
    nscan_local <<<512, 512, 0, stream>>>(gg, nend, Dend);
    nscan_stitch<<<  8, 512, 0, stream>>>(nend, Dend, n0a, nfO);
    denom_kernel<<<128, 256, 0, stream>>>(qkv, gg, n0a, invd);
    chunk_prep<<<256, 512, 0, stream>>>(qkv, gg);
    chunk_A<<<256, 256, 0, stream>>>(qkv, gg, hsb);
    for (int c0 = 0; c0 < NCT; c0 += nc) {
        chunk_state<<<256, 256, 0, stream>>>(qkv, gg, snap, Cst, CfO, c0, nc);
        chunk_h2<<<dim3(2, nc, 8), 256, 0, stream>>>(qkv, gg, snap, invd, hsb, hlO, c0);
    }
    gemm_act<2><<<dim3(4, 64), 256, 0, stream>>>(
        hsb, 512, W_out, W_out, W_out, b_out, b_out, b_out, out, 512);
}